// Round 1
// baseline (1472.500 us; speedup 1.0000x reference)
//
#include <hip/hip_runtime.h>
#include <cstdint>
#include <cstddef>

typedef unsigned int u32;
typedef unsigned long long u64;

#define NUM_EL 2359296
#define N_ROWS 294912
#define N_OPS  262144
#define OFF1   1048576
#define OFF2   2097152

// ---------------- workspace layout (bytes) ----------------
// addr:      [0, 9437184)                       u32[NUM_EL]  (final argsort values)
// mem/memf:  [9437184, 84934656)                float[NUM_EL*8]  (also sort scratch before conv)
//   kA  = mem+0, kB = mem+9437184, vB = mem+18874368        (sort1; vA = addr)
//   k2A = mem+0, k2B = +1MB, v2A = +2MB, v2B = +3MB         (sort2, mem dead by then)
// counts:    [84934656, 85524480)               u32[256*576]
// partials:  [85524480, 87883776)               float[64*9216]
// flat:      [87883776, 87884800)               float[256]
// wt:        [87884800, 87889408)               float[1152]
// pen:       [87889408, 87889424)               double[2]
#define OFF_MEM    9437184ull
#define OFF_COUNTS 84934656ull
#define OFF_PART   85524480ull
#define OFF_FLAT   87883776ull
#define OFF_WT     87884800ull
#define OFF_PEN    87889408ull

__global__ void k_init(double* pen) {
  if (threadIdx.x < 2) pen[threadIdx.x] = 0.0;
}

// keys: float -> order-preserving u32; vals = identity
__global__ __launch_bounds__(256) void k_make_keys(const float* __restrict__ x,
                                                   u32* __restrict__ keys,
                                                   u32* __restrict__ vals, int n) {
  int i = blockIdx.x * 256 + threadIdx.x;
  if (i < n) {
    u32 u = __float_as_uint(x[i]);
    u = (u & 0x80000000u) ? ~u : (u | 0x80000000u);
    keys[i] = u;
    vals[i] = (u32)i;
  }
}

// per-block 256-bucket histogram; tile = 4096 elements, grid*4096 == n exactly
__global__ __launch_bounds__(256) void k_hist(const u32* __restrict__ keys,
                                              u32* __restrict__ counts, int shift, int nB) {
  __shared__ u32 h[256];
  int t = threadIdx.x;
  h[t] = 0;
  __syncthreads();
  int base = blockIdx.x * 4096;
#pragma unroll
  for (int k = 0; k < 16; k++) {
    u32 d = (keys[base + t + k * 256] >> shift) & 255u;
    atomicAdd(&h[d], 1u);
  }
  __syncthreads();
  counts[t * nB + blockIdx.x] = h[t];  // digit-major
}

// in-place: counts[d][b] -> global start position of (digit d, block b). 1 block, 256 thr.
__global__ __launch_bounds__(256) void k_scan(u32* __restrict__ counts, int nB) {
  int d = threadIdx.x;
  u32* p = counts + d * nB;
  u32 run = 0;
  for (int b = 0; b < nB; b += 8) {
    uint4 a = *(uint4*)(p + b);
    uint4 c = *(uint4*)(p + b + 4);
    u32 t;
    t = a.x; a.x = run; run += t;
    t = a.y; a.y = run; run += t;
    t = a.z; a.z = run; run += t;
    t = a.w; a.w = run; run += t;
    t = c.x; c.x = run; run += t;
    t = c.y; c.y = run; run += t;
    t = c.z; c.z = run; run += t;
    t = c.w; c.w = run; run += t;
    *(uint4*)(p + b) = a;
    *(uint4*)(p + b + 4) = c;
  }
  __shared__ u32 tot[256];
  tot[d] = run;
  __syncthreads();
  for (int off = 1; off < 256; off <<= 1) {
    u32 v = (d >= off) ? tot[d - off] : 0u;
    __syncthreads();
    tot[d] += v;
    __syncthreads();
  }
  u32 base = tot[d] - run;  // exclusive digit base
  for (int b = 0; b < nB; b += 8) {
    uint4 a = *(uint4*)(p + b);
    uint4 c = *(uint4*)(p + b + 4);
    a.x += base; a.y += base; a.z += base; a.w += base;
    c.x += base; c.y += base; c.z += base; c.w += base;
    *(uint4*)(p + b) = a;
    *(uint4*)(p + b + 4) = c;
  }
}

// stable scatter: each wave owns a contiguous 1024-elem region, 16 rounds of 64
__global__ __launch_bounds__(256) void k_scatter(const u32* __restrict__ kin, const u32* __restrict__ vin,
                                                 u32* __restrict__ kout, u32* __restrict__ vout,
                                                 const u32* __restrict__ gbase, int shift, int nB) {
  __shared__ u32 skeys[4096], svals[4096];
  __shared__ u32 whist[4][256];
  __shared__ u32 sbase[256];
  int t = threadIdx.x, b = blockIdx.x;
  int base = b * 4096;
#pragma unroll
  for (int k = 0; k < 16; k++) {
    int idx = t + k * 256;
    skeys[idx] = kin[base + idx];
    svals[idx] = vin[base + idx];
  }
#pragma unroll
  for (int w = 0; w < 4; w++) whist[w][t] = 0;
  sbase[t] = gbase[t * nB + b];
  __syncthreads();
  int w = t >> 6, lane = t & 63;
  u64 lowmask = (1ull << lane) - 1ull;
  u32 dig[16], rnk[16];
#pragma unroll
  for (int j = 0; j < 16; j++) {
    int idx = w * 1024 + j * 64 + lane;
    u32 d = (skeys[idx] >> shift) & 255u;
    u64 m = ~0ull;
#pragma unroll
    for (int bit = 0; bit < 8; bit++) {
      u64 bal = __ballot((d >> bit) & 1u);
      m &= ((d >> bit) & 1u) ? bal : ~bal;
    }
    u32 rr = (u32)__popcll(m & lowmask);
    u32 cnt = (u32)__popcll(m);
    u32 prev = whist[w][d];        // wave-synchronous read (in-order LDS within wave)
    if (rr == 0) whist[w][d] = prev + cnt;  // one leader per digit per round
    dig[j] = d;
    rnk[j] = prev + rr;
  }
  __syncthreads();
  {  // cross-wave exclusive prefix per digit (thread t = digit)
    u32 s = 0;
    for (int ww = 0; ww < 4; ww++) { u32 v = whist[ww][t]; whist[ww][t] = s; s += v; }
  }
  __syncthreads();
#pragma unroll
  for (int j = 0; j < 16; j++) {
    int idx = w * 1024 + j * 64 + lane;
    u32 d = dig[j];
    u32 pos = sbase[d] + whist[w][d] + rnk[j];
    kout[pos] = skeys[idx];
    vout[pos] = svals[idx];
  }
}

// 1->8ch 3x3 SAME conv on addr-as-float image, relu, scatter to memf[addr[i]*8 + c]
__global__ __launch_bounds__(256) void k_conv_scatter(const u32* __restrict__ addr,
                                                      const float* __restrict__ cw,
                                                      const float* __restrict__ cb,
                                                      float* __restrict__ memf,
                                                      int H, int W, int lw, int off) {
  int pix = blockIdx.x * 256 + threadIdx.x;
  int i = pix >> lw, j = pix & (W - 1);
  float x[3][3];
#pragma unroll
  for (int dr = 0; dr < 3; dr++)
#pragma unroll
    for (int dc = 0; dc < 3; dc++) {
      int r = i + dr - 1, c = j + dc - 1;
      bool inb = ((unsigned)r < (unsigned)H) && ((unsigned)c < (unsigned)W);
      x[dr][dc] = inb ? (float)addr[off + r * W + c] : 0.0f;
    }
  u32 a = addr[off + pix];
  float acc[8];
#pragma unroll
  for (int oc = 0; oc < 8; oc++) {
    float s = cb[oc];
#pragma unroll
    for (int dr = 0; dr < 3; dr++)
#pragma unroll
      for (int dc = 0; dc < 3; dc++)
        s = fmaf(x[dr][dc], cw[oc * 9 + dr * 3 + dc], s);
    acc[oc] = fmaxf(s, 0.0f);
  }
  float4* dst = (float4*)(memf + (size_t)a * 8);
  dst[0] = make_float4(acc[0], acc[1], acc[2], acc[3]);
  dst[1] = make_float4(acc[4], acc[5], acc[6], acc[7]);
}

// transpose mem_w [16][8][3][3] -> wt[(dr*3+dl)*8+ic][16] (oc contiguous)
__global__ void k_wt(const float* __restrict__ mw, float* __restrict__ wt) {
  int i = threadIdx.x + blockIdx.x * 256;
  if (i < 1152) {
    int oc = i & 15;
    int rest = i >> 4;          // (dr*3+dl)*8 + ic
    int ic = rest & 7;
    int p = rest >> 3;          // dr*3+dl
    int dr = p / 3, dl = p % 3;
    wt[i] = mw[((oc * 8 + ic) * 3 + dr) * 3 + dl];
  }
}

// 8->16ch 3x3 SAME conv on [N_ROWS x 8] (channel-last), relu, fused 4x4 pool partials.
// Block = 32 rows x 8 lanes. blocks = 9216. partials[(oc*4+lb)*9216 + blk]
__global__ __launch_bounds__(256) void k_memconv(const float* __restrict__ memf,
                                                 const float* __restrict__ wt,
                                                 const float* __restrict__ mb,
                                                 float* __restrict__ partials) {
  __shared__ float tile[34 * 80];    // 34 rows x (10 lanes x 8ch), lane pads zeroed
  __shared__ float pool_s[256 * 17]; // [thread][oc], pad 17 to dodge bank conflicts
  int t = threadIdx.x;
  int r0 = blockIdx.x * 32;
  for (int idx = t; idx < 34 * 64; idx += 256) {
    int rr = idx >> 6, cc = idx & 63;
    int r = r0 - 1 + rr;
    float v = ((unsigned)r < (unsigned)N_ROWS) ? memf[(size_t)r * 64 + cc] : 0.0f;
    int l = cc >> 3, c = cc & 7;
    tile[rr * 80 + (l + 1) * 8 + c] = v;
  }
  for (int idx = t; idx < 34 * 16; idx += 256) {
    int rr = idx >> 4, k = idx & 15;
    int col = (k < 8) ? k : (64 + k);  // lanes -1 and 8 (padded idx 0 and 9)
    tile[rr * 80 + col] = 0.0f;
  }
  __syncthreads();
  int lr = t >> 3, l = t & 7;
  float acc[16];
#pragma unroll
  for (int oc = 0; oc < 16; oc++) acc[oc] = mb[oc];
#pragma unroll
  for (int dr = 0; dr < 3; dr++) {
#pragma unroll
    for (int dl = 0; dl < 3; dl++) {
      const float* src = &tile[(lr + dr) * 80 + (l + dl) * 8];
      float4 a0 = *(const float4*)(src);
      float4 a1 = *(const float4*)(src + 4);
      float xv[8] = {a0.x, a0.y, a0.z, a0.w, a1.x, a1.y, a1.z, a1.w};
      const float* wp = &wt[(dr * 3 + dl) * 128];
#pragma unroll
      for (int ic = 0; ic < 8; ic++) {
#pragma unroll
        for (int oc = 0; oc < 16; oc++)
          acc[oc] = fmaf(xv[ic], wp[ic * 16 + oc], acc[oc]);
      }
    }
  }
#pragma unroll
  for (int oc = 0; oc < 16; oc++) pool_s[t * 17 + oc] = fmaxf(acc[oc], 0.0f);
  __syncthreads();
  if (t < 64) {
    int oc = t >> 2, lb = t & 3;
    float s = 0.0f;
    for (int lr2 = 0; lr2 < 32; lr2++) {
      int t2 = lr2 * 8 + lb * 2;
      s += pool_s[t2 * 17 + oc] + pool_s[(t2 + 1) * 17 + oc];
    }
    partials[(size_t)(oc * 4 + lb) * 9216 + blockIdx.x] = s;
  }
}

// 256 blocks, one per pooled cell f = oc*16 + rb*4 + lb; mean over 147456 pixels
__global__ __launch_bounds__(256) void k_pool_final(const float* __restrict__ partials,
                                                    float* __restrict__ flat) {
  int f = blockIdx.x;
  int oc = f >> 4, rb = (f >> 2) & 3, lb = f & 3;
  const float* src = partials + (size_t)(oc * 4 + lb) * 9216 + rb * 2304;
  double s = 0.0;
  for (int i = threadIdx.x; i < 2304; i += 256) s += (double)src[i];
  __shared__ double sd[256];
  sd[threadIdx.x] = s;
  __syncthreads();
  for (int off = 128; off > 0; off >>= 1) {
    if (threadIdx.x < off) sd[threadIdx.x] += sd[threadIdx.x + off];
    __syncthreads();
  }
  if (threadIdx.x == 0) flat[f] = (float)(sd[0] * (1.0 / 147456.0));
}

// one wave per 32 rows of proj_w [N_OPS][256]; fully coalesced 1KB row reads
__global__ __launch_bounds__(256) void k_matvec(const float* __restrict__ pw,
                                                const float* __restrict__ pb,
                                                const float* __restrict__ flat,
                                                float* __restrict__ out) {
  int t = threadIdx.x;
  int lane = t & 63;
  int g = (blockIdx.x * 256 + t) >> 6;  // wave id 0..8191
  float4 f4 = ((const float4*)flat)[lane];
  int row0 = g * 32;
  for (int it = 0; it < 32; it++) {
    int row = row0 + it;
    float4 w4 = ((const float4*)(pw + (size_t)row * 256))[lane];
    float s = w4.x * f4.x + w4.y * f4.y + w4.z * f4.z + w4.w * f4.w;
#pragma unroll
    for (int off = 32; off > 0; off >>= 1) s += __shfl_xor(s, off, 64);
    if (lane == 0) out[row] = s + pb[row];
  }
}

__device__ inline double staged_pair(float x) {
  // staged(relu(x), e=1) + staged(relu(-x), e=2)
  float h = fabsf(x);
  double mult = (h <= 2.f) ? 1.0 : (h <= 4.f) ? 1.5 : (h <= 8.f) ? 2.0 : (h <= 16.f) ? 3.0 : 5.0;
  double hh = (double)h;
  if (x > 0.f) return hh * mult;
  if (x < 0.f) return hh * hh * mult;
  return 0.0;
}

__global__ __launch_bounds__(256) void k_penalty(const u32* __restrict__ order,
                                                 const u32* __restrict__ addr,
                                                 double* __restrict__ pen) {
  int k = blockIdx.x * 256 + threadIdx.x;
  u32 r = order[k];
  int i = (int)(r >> 9), j = (int)(r & 511);
  float A0 = (float)addr[(i << 10) + j];
  float A1 = (float)addr[OFF1 + (i << 10) + j];
  float A2 = (float)addr[OFF2 + (int)r];
  double intra = staged_pair(A1 - A0) + staged_pair(A2 - A1);
  double inter = 0.0;
  if (k < N_OPS - 1) {
    u32 r2 = order[k + 1];
    int i2 = (int)(r2 >> 9), j2 = (int)(r2 & 511);
    float B0 = (float)addr[(i2 << 10) + j2];
    inter = staged_pair(B0 - A2);
  }
  __shared__ double s0[256], s1[256];
  s0[threadIdx.x] = inter;
  s1[threadIdx.x] = intra;
  __syncthreads();
  for (int off = 128; off > 0; off >>= 1) {
    if (threadIdx.x < off) {
      s0[threadIdx.x] += s0[threadIdx.x + off];
      s1[threadIdx.x] += s1[threadIdx.x + off];
    }
    __syncthreads();
  }
  if (threadIdx.x == 0) {
    atomicAdd(&pen[0], s0[0]);
    atomicAdd(&pen[1], s1[0]);
  }
}

__global__ void k_finalize(const double* __restrict__ pen, float* __restrict__ out) {
  if (threadIdx.x == 0) {
    out[N_OPS] = (float)pen[0];
    out[N_OPS + 1] = (float)pen[1];
  }
}

extern "C" void kernel_launch(void* const* d_in, const int* in_sizes, int n_in,
                              void* d_out, int out_size, void* d_ws, size_t ws_size,
                              hipStream_t stream) {
  const float* mem_logits = (const float*)d_in[0];
  const float* cw0 = (const float*)d_in[1];
  const float* cb0 = (const float*)d_in[2];
  const float* cw1 = (const float*)d_in[3];
  const float* cb1 = (const float*)d_in[4];
  const float* cw2 = (const float*)d_in[5];
  const float* cb2 = (const float*)d_in[6];
  const float* mw  = (const float*)d_in[7];
  const float* mbb = (const float*)d_in[8];
  const float* pw  = (const float*)d_in[9];
  const float* pb  = (const float*)d_in[10];
  float* out = (float*)d_out;
  char* ws = (char*)d_ws;

  u32* addr      = (u32*)(ws);
  float* memf    = (float*)(ws + OFF_MEM);
  u32* kA        = (u32*)(ws + OFF_MEM);
  u32* kB        = (u32*)(ws + OFF_MEM + 9437184ull);
  u32* vB        = (u32*)(ws + OFF_MEM + 18874368ull);
  u32* counts    = (u32*)(ws + OFF_COUNTS);
  float* partials= (float*)(ws + OFF_PART);
  float* flat    = (float*)(ws + OFF_FLAT);
  float* wt      = (float*)(ws + OFF_WT);
  double* pen    = (double*)(ws + OFF_PEN);
  u32* k2A       = (u32*)(ws + OFF_MEM);
  u32* k2B       = (u32*)(ws + OFF_MEM + 1048576ull);
  u32* v2A       = (u32*)(ws + OFF_MEM + 2097152ull);
  u32* v2B       = (u32*)(ws + OFF_MEM + 3145728ull);

  k_init<<<1, 64, 0, stream>>>(pen);

  // ---- sort 1: addr = stable argsort(mem_logits), 2359296 elems, 576 tiles ----
  k_make_keys<<<9216, 256, 0, stream>>>(mem_logits, kA, addr, NUM_EL);
  const u32* ki[4] = {kA, kB, kA, kB};
  const u32* vi[4] = {addr, vB, addr, vB};
  u32* ko[4] = {kB, kA, kB, kA};
  u32* vo[4] = {vB, addr, vB, addr};
  for (int p = 0; p < 4; p++) {
    k_hist<<<576, 256, 0, stream>>>(ki[p], counts, p * 8, 576);
    k_scan<<<1, 256, 0, stream>>>(counts, 576);
    k_scatter<<<576, 256, 0, stream>>>(ki[p], vi[p], ko[p], vo[p], counts, p * 8, 576);
  }
  // final vals land in addr after pass 3

  // ---- convs + scatter into memf (overwrites sort scratch; addr preserved) ----
  k_conv_scatter<<<4096, 256, 0, stream>>>(addr, cw0, cb0, memf, 1024, 1024, 10, 0);
  k_conv_scatter<<<4096, 256, 0, stream>>>(addr, cw1, cb1, memf, 1024, 1024, 10, OFF1);
  k_conv_scatter<<<1024, 256, 0, stream>>>(addr, cw2, cb2, memf, 512, 512, 9, OFF2);

  // ---- mem conv (8->16) fused with 4x4 adaptive pool ----
  k_wt<<<5, 256, 0, stream>>>(mw, wt);
  k_memconv<<<9216, 256, 0, stream>>>(memf, wt, mbb, partials);
  k_pool_final<<<256, 256, 0, stream>>>(partials, flat);

  // ---- projection matvec -> op_logits in d_out[0..N_OPS) ----
  k_matvec<<<2048, 256, 0, stream>>>(pw, pb, flat, out);

  // ---- sort 2: order = stable argsort(op_logits), 262144 elems, 64 tiles ----
  k_make_keys<<<1024, 256, 0, stream>>>(out, k2A, v2A, N_OPS);
  const u32* ki2[4] = {k2A, k2B, k2A, k2B};
  const u32* vi2[4] = {v2A, v2B, v2A, v2B};
  u32* ko2[4] = {k2B, k2A, k2B, k2A};
  u32* vo2[4] = {v2B, v2A, v2B, v2A};
  for (int p = 0; p < 4; p++) {
    k_hist<<<64, 256, 0, stream>>>(ki2[p], counts, p * 8, 64);
    k_scan<<<1, 256, 0, stream>>>(counts, 64);
    k_scatter<<<64, 256, 0, stream>>>(ki2[p], vi2[p], ko2[p], vo2[p], counts, p * 8, 64);
  }
  // order in v2A

  // ---- penalties ----
  k_penalty<<<1024, 256, 0, stream>>>(v2A, addr, pen);
  k_finalize<<<1, 64, 0, stream>>>(pen, out);
}

// Round 2
// 1130.013 us; speedup vs baseline: 1.3031x; 1.3031x over previous
//
#include <hip/hip_runtime.h>
#include <cstdint>
#include <cstddef>

typedef unsigned int u32;
typedef unsigned long long u64;

#define NUM_EL 2359296
#define N_ROWS 294912
#define N_OPS  262144
#define OFF1   1048576
#define OFF2   2097152

// ---------------- workspace layout (bytes) ----------------
// addr:      [0, 9437184)                       u32[NUM_EL]  (final argsort values)
// mem/memf:  [9437184, 84934656)                float[NUM_EL*8]  (also sort scratch before conv)
//   kA  = mem+0, kB = mem+9437184, vB = mem+18874368        (sort1; vA = addr)
//   k2A = mem+0, k2B = +1MB, v2A = +2MB, v2B = +3MB         (sort2, mem dead by then)
// counts:    [84934656, 85524480)               u32[256*576]
// pos:       [85524480, 86114304)               u32[256*576]  (scanned offsets)
// partials:  [86114304, 88473600)               float[64*9216]
// flat:      [88473600, 88474624)               float[256]
// wt:        [88474624, 88479232)               float[1152]
// pen:       [88479232, 88479248)               double[2]
#define OFF_MEM    9437184ull
#define OFF_COUNTS 84934656ull
#define OFF_POS    85524480ull
#define OFF_PART   86114304ull
#define OFF_FLAT   88473600ull
#define OFF_WT     88474624ull
#define OFF_PEN    88479232ull

__global__ void k_init(double* pen) {
  if (threadIdx.x < 2) pen[threadIdx.x] = 0.0;
}

// keys: float -> order-preserving u32; vals = identity
__global__ __launch_bounds__(256) void k_make_keys(const float* __restrict__ x,
                                                   u32* __restrict__ keys,
                                                   u32* __restrict__ vals, int n) {
  int i = blockIdx.x * 256 + threadIdx.x;
  if (i < n) {
    u32 u = __float_as_uint(x[i]);
    u = (u & 0x80000000u) ? ~u : (u | 0x80000000u);
    keys[i] = u;
    vals[i] = (u32)i;
  }
}

// per-block 256-bucket histogram; tile = 4096 elements, grid*4096 == n exactly
__global__ __launch_bounds__(256) void k_hist(const u32* __restrict__ keys,
                                              u32* __restrict__ counts, int shift, int nB) {
  __shared__ u32 h[256];
  int t = threadIdx.x;
  h[t] = 0;
  __syncthreads();
  int base = blockIdx.x * 4096;
#pragma unroll
  for (int k = 0; k < 16; k++) {
    u32 d = (keys[base + t + k * 256] >> shift) & 255u;
    atomicAdd(&h[d], 1u);
  }
  __syncthreads();
  counts[t * nB + blockIdx.x] = h[t];  // digit-major
}

// Parallel scan: 256 blocks (one per digit). Digit-major layout means the
// global base of digit d is the sum of the CONTIGUOUS prefix counts[0, d*nB).
// Row scan done in LDS. Output to separate pos[] (no cross-block race).
__global__ __launch_bounds__(256) void k_scan_par(const u32* __restrict__ counts,
                                                  u32* __restrict__ pos, int nB) {
  int d = blockIdx.x, t = threadIdx.x;
  __shared__ u32 red[256];
  // ---- base = sum of counts[0 .. d*nB) ----
  u32 s = 0;
  u32 lim = (u32)(d * nB);
  for (u32 i = t; i < lim; i += 256) s += counts[i];
  red[t] = s;
  __syncthreads();
  for (int off = 128; off > 0; off >>= 1) {
    if (t < off) red[t] += red[t + off];
    __syncthreads();
  }
  u32 base = red[0];
  __syncthreads();
  // ---- exclusive scan of row d (nB values), chunk per thread ----
  int chunk = (nB + 255) / 256;  // 3 for nB=576, 1 for nB=64
  int i0 = t * chunk;
  u32 loc[4];
  u32 lsum = 0;
#pragma unroll 4
  for (int k = 0; k < chunk; k++) {
    int i = i0 + k;
    u32 v = (i < nB) ? counts[d * nB + i] : 0u;
    loc[k] = lsum;
    lsum += v;
  }
  red[t] = lsum;
  __syncthreads();
  for (int off = 1; off < 256; off <<= 1) {
    u32 y = (t >= off) ? red[t - off] : 0u;
    __syncthreads();
    red[t] += y;
    __syncthreads();
  }
  u32 excl = red[t] - lsum;  // exclusive prefix across threads
#pragma unroll 4
  for (int k = 0; k < chunk; k++) {
    int i = i0 + k;
    if (i < nB) pos[d * nB + i] = base + excl + loc[k];
  }
}

// stable scatter: each wave owns a contiguous 1024-elem region, 16 rounds of 64
__global__ __launch_bounds__(256) void k_scatter(const u32* __restrict__ kin, const u32* __restrict__ vin,
                                                 u32* __restrict__ kout, u32* __restrict__ vout,
                                                 const u32* __restrict__ gbase, int shift, int nB) {
  __shared__ u32 skeys[4096], svals[4096];
  __shared__ u32 whist[4][256];
  __shared__ u32 sbase[256];
  int t = threadIdx.x, b = blockIdx.x;
  int base = b * 4096;
#pragma unroll
  for (int k = 0; k < 16; k++) {
    int idx = t + k * 256;
    skeys[idx] = kin[base + idx];
    svals[idx] = vin[base + idx];
  }
#pragma unroll
  for (int w = 0; w < 4; w++) whist[w][t] = 0;
  sbase[t] = gbase[t * nB + b];
  __syncthreads();
  int w = t >> 6, lane = t & 63;
  u64 lowmask = (1ull << lane) - 1ull;
  u32 dig[16], rnk[16];
#pragma unroll
  for (int j = 0; j < 16; j++) {
    int idx = w * 1024 + j * 64 + lane;
    u32 d = (skeys[idx] >> shift) & 255u;
    u64 m = ~0ull;
#pragma unroll
    for (int bit = 0; bit < 8; bit++) {
      u64 bal = __ballot((d >> bit) & 1u);
      m &= ((d >> bit) & 1u) ? bal : ~bal;
    }
    u32 rr = (u32)__popcll(m & lowmask);
    u32 cnt = (u32)__popcll(m);
    u32 prev = whist[w][d];        // wave-synchronous read (in-order LDS within wave)
    if (rr == 0) whist[w][d] = prev + cnt;  // one leader per digit per round
    dig[j] = d;
    rnk[j] = prev + rr;
  }
  __syncthreads();
  {  // cross-wave exclusive prefix per digit (thread t = digit)
    u32 s = 0;
    for (int ww = 0; ww < 4; ww++) { u32 v = whist[ww][t]; whist[ww][t] = s; s += v; }
  }
  __syncthreads();
#pragma unroll
  for (int j = 0; j < 16; j++) {
    int idx = w * 1024 + j * 64 + lane;
    u32 d = dig[j];
    u32 pos = sbase[d] + whist[w][d] + rnk[j];
    kout[pos] = skeys[idx];
    vout[pos] = svals[idx];
  }
}

// 1->8ch 3x3 SAME conv on addr-as-float image, relu, scatter to memf[addr[i]*8 + c]
__global__ __launch_bounds__(256) void k_conv_scatter(const u32* __restrict__ addr,
                                                      const float* __restrict__ cw,
                                                      const float* __restrict__ cb,
                                                      float* __restrict__ memf,
                                                      int H, int W, int lw, int off) {
  int pix = blockIdx.x * 256 + threadIdx.x;
  int i = pix >> lw, j = pix & (W - 1);
  float x[3][3];
#pragma unroll
  for (int dr = 0; dr < 3; dr++)
#pragma unroll
    for (int dc = 0; dc < 3; dc++) {
      int r = i + dr - 1, c = j + dc - 1;
      bool inb = ((unsigned)r < (unsigned)H) && ((unsigned)c < (unsigned)W);
      x[dr][dc] = inb ? (float)addr[off + r * W + c] : 0.0f;
    }
  u32 a = addr[off + pix];
  float acc[8];
#pragma unroll
  for (int oc = 0; oc < 8; oc++) {
    float s = cb[oc];
#pragma unroll
    for (int dr = 0; dr < 3; dr++)
#pragma unroll
      for (int dc = 0; dc < 3; dc++)
        s = fmaf(x[dr][dc], cw[oc * 9 + dr * 3 + dc], s);
    acc[oc] = fmaxf(s, 0.0f);
  }
  float4* dst = (float4*)(memf + (size_t)a * 8);
  dst[0] = make_float4(acc[0], acc[1], acc[2], acc[3]);
  dst[1] = make_float4(acc[4], acc[5], acc[6], acc[7]);
}

// transpose mem_w [16][8][3][3] -> wt[(dr*3+dl)*8+ic][16] (oc contiguous)
__global__ void k_wt(const float* __restrict__ mw, float* __restrict__ wt) {
  int i = threadIdx.x + blockIdx.x * 256;
  if (i < 1152) {
    int oc = i & 15;
    int rest = i >> 4;          // (dr*3+dl)*8 + ic
    int ic = rest & 7;
    int p = rest >> 3;          // dr*3+dl
    int dr = p / 3, dl = p % 3;
    wt[i] = mw[((oc * 8 + ic) * 3 + dr) * 3 + dl];
  }
}

// 8->16ch 3x3 SAME conv on [N_ROWS x 8] (channel-last), relu, fused 4x4 pool partials.
// Block = 32 rows x 8 lanes. blocks = 9216. partials[(oc*4+lb)*9216 + blk]
__global__ __launch_bounds__(256) void k_memconv(const float* __restrict__ memf,
                                                 const float* __restrict__ wt,
                                                 const float* __restrict__ mb,
                                                 float* __restrict__ partials) {
  __shared__ float tile[34 * 80];    // 34 rows x (10 lanes x 8ch), lane pads zeroed
  __shared__ float pool_s[256 * 17]; // [thread][oc], pad 17 to dodge bank conflicts
  int t = threadIdx.x;
  int r0 = blockIdx.x * 32;
  for (int idx = t; idx < 34 * 64; idx += 256) {
    int rr = idx >> 6, cc = idx & 63;
    int r = r0 - 1 + rr;
    float v = ((unsigned)r < (unsigned)N_ROWS) ? memf[(size_t)r * 64 + cc] : 0.0f;
    int l = cc >> 3, c = cc & 7;
    tile[rr * 80 + (l + 1) * 8 + c] = v;
  }
  for (int idx = t; idx < 34 * 16; idx += 256) {
    int rr = idx >> 4, k = idx & 15;
    int col = (k < 8) ? k : (64 + k);  // lanes -1 and 8 (padded idx 0 and 9)
    tile[rr * 80 + col] = 0.0f;
  }
  __syncthreads();
  int lr = t >> 3, l = t & 7;
  float acc[16];
#pragma unroll
  for (int oc = 0; oc < 16; oc++) acc[oc] = mb[oc];
#pragma unroll
  for (int dr = 0; dr < 3; dr++) {
#pragma unroll
    for (int dl = 0; dl < 3; dl++) {
      const float* src = &tile[(lr + dr) * 80 + (l + dl) * 8];
      float4 a0 = *(const float4*)(src);
      float4 a1 = *(const float4*)(src + 4);
      float xv[8] = {a0.x, a0.y, a0.z, a0.w, a1.x, a1.y, a1.z, a1.w};
      const float* wp = &wt[(dr * 3 + dl) * 128];
#pragma unroll
      for (int ic = 0; ic < 8; ic++) {
#pragma unroll
        for (int oc = 0; oc < 16; oc++)
          acc[oc] = fmaf(xv[ic], wp[ic * 16 + oc], acc[oc]);
      }
    }
  }
#pragma unroll
  for (int oc = 0; oc < 16; oc++) pool_s[t * 17 + oc] = fmaxf(acc[oc], 0.0f);
  __syncthreads();
  if (t < 64) {
    int oc = t >> 2, lb = t & 3;
    float s = 0.0f;
    for (int lr2 = 0; lr2 < 32; lr2++) {
      int t2 = lr2 * 8 + lb * 2;
      s += pool_s[t2 * 17 + oc] + pool_s[(t2 + 1) * 17 + oc];
    }
    partials[(size_t)(oc * 4 + lb) * 9216 + blockIdx.x] = s;
  }
}

// 256 blocks, one per pooled cell f = oc*16 + rb*4 + lb; mean over 147456 pixels
__global__ __launch_bounds__(256) void k_pool_final(const float* __restrict__ partials,
                                                    float* __restrict__ flat) {
  int f = blockIdx.x;
  int oc = f >> 4, rb = (f >> 2) & 3, lb = f & 3;
  const float* src = partials + (size_t)(oc * 4 + lb) * 9216 + rb * 2304;
  double s = 0.0;
  for (int i = threadIdx.x; i < 2304; i += 256) s += (double)src[i];
  __shared__ double sd[256];
  sd[threadIdx.x] = s;
  __syncthreads();
  for (int off = 128; off > 0; off >>= 1) {
    if (threadIdx.x < off) sd[threadIdx.x] += sd[threadIdx.x + off];
    __syncthreads();
  }
  if (threadIdx.x == 0) flat[f] = (float)(sd[0] * (1.0 / 147456.0));
}

// one wave per 32 rows of proj_w [N_OPS][256]; fully coalesced 1KB row reads
__global__ __launch_bounds__(256) void k_matvec(const float* __restrict__ pw,
                                                const float* __restrict__ pb,
                                                const float* __restrict__ flat,
                                                float* __restrict__ out) {
  int t = threadIdx.x;
  int lane = t & 63;
  int g = (blockIdx.x * 256 + t) >> 6;  // wave id 0..8191
  float4 f4 = ((const float4*)flat)[lane];
  int row0 = g * 32;
  for (int it = 0; it < 32; it++) {
    int row = row0 + it;
    float4 w4 = ((const float4*)(pw + (size_t)row * 256))[lane];
    float s = w4.x * f4.x + w4.y * f4.y + w4.z * f4.z + w4.w * f4.w;
#pragma unroll
    for (int off = 32; off > 0; off >>= 1) s += __shfl_xor(s, off, 64);
    if (lane == 0) out[row] = s + pb[row];
  }
}

__device__ inline double staged_pair(float x) {
  // staged(relu(x), e=1) + staged(relu(-x), e=2)
  float h = fabsf(x);
  double mult = (h <= 2.f) ? 1.0 : (h <= 4.f) ? 1.5 : (h <= 8.f) ? 2.0 : (h <= 16.f) ? 3.0 : 5.0;
  double hh = (double)h;
  if (x > 0.f) return hh * mult;
  if (x < 0.f) return hh * hh * mult;
  return 0.0;
}

__global__ __launch_bounds__(256) void k_penalty(const u32* __restrict__ order,
                                                 const u32* __restrict__ addr,
                                                 double* __restrict__ pen) {
  int k = blockIdx.x * 256 + threadIdx.x;
  u32 r = order[k];
  int i = (int)(r >> 9), j = (int)(r & 511);
  float A0 = (float)addr[(i << 10) + j];
  float A1 = (float)addr[OFF1 + (i << 10) + j];
  float A2 = (float)addr[OFF2 + (int)r];
  double intra = staged_pair(A1 - A0) + staged_pair(A2 - A1);
  double inter = 0.0;
  if (k < N_OPS - 1) {
    u32 r2 = order[k + 1];
    int i2 = (int)(r2 >> 9), j2 = (int)(r2 & 511);
    float B0 = (float)addr[(i2 << 10) + j2];
    inter = staged_pair(B0 - A2);
  }
  __shared__ double s0[256], s1[256];
  s0[threadIdx.x] = inter;
  s1[threadIdx.x] = intra;
  __syncthreads();
  for (int off = 128; off > 0; off >>= 1) {
    if (threadIdx.x < off) {
      s0[threadIdx.x] += s0[threadIdx.x + off];
      s1[threadIdx.x] += s1[threadIdx.x + off];
    }
    __syncthreads();
  }
  if (threadIdx.x == 0) {
    atomicAdd(&pen[0], s0[0]);
    atomicAdd(&pen[1], s1[0]);
  }
}

__global__ void k_finalize(const double* __restrict__ pen, float* __restrict__ out) {
  if (threadIdx.x == 0) {
    out[N_OPS] = (float)pen[0];
    out[N_OPS + 1] = (float)pen[1];
  }
}

extern "C" void kernel_launch(void* const* d_in, const int* in_sizes, int n_in,
                              void* d_out, int out_size, void* d_ws, size_t ws_size,
                              hipStream_t stream) {
  const float* mem_logits = (const float*)d_in[0];
  const float* cw0 = (const float*)d_in[1];
  const float* cb0 = (const float*)d_in[2];
  const float* cw1 = (const float*)d_in[3];
  const float* cb1 = (const float*)d_in[4];
  const float* cw2 = (const float*)d_in[5];
  const float* cb2 = (const float*)d_in[6];
  const float* mw  = (const float*)d_in[7];
  const float* mbb = (const float*)d_in[8];
  const float* pw  = (const float*)d_in[9];
  const float* pb  = (const float*)d_in[10];
  float* out = (float*)d_out;
  char* ws = (char*)d_ws;

  u32* addr      = (u32*)(ws);
  float* memf    = (float*)(ws + OFF_MEM);
  u32* kA        = (u32*)(ws + OFF_MEM);
  u32* kB        = (u32*)(ws + OFF_MEM + 9437184ull);
  u32* vB        = (u32*)(ws + OFF_MEM + 18874368ull);
  u32* counts    = (u32*)(ws + OFF_COUNTS);
  u32* pos       = (u32*)(ws + OFF_POS);
  float* partials= (float*)(ws + OFF_PART);
  float* flat    = (float*)(ws + OFF_FLAT);
  float* wt      = (float*)(ws + OFF_WT);
  double* pen    = (double*)(ws + OFF_PEN);
  u32* k2A       = (u32*)(ws + OFF_MEM);
  u32* k2B       = (u32*)(ws + OFF_MEM + 1048576ull);
  u32* v2A       = (u32*)(ws + OFF_MEM + 2097152ull);
  u32* v2B       = (u32*)(ws + OFF_MEM + 3145728ull);

  k_init<<<1, 64, 0, stream>>>(pen);

  // ---- sort 1: addr = stable argsort(mem_logits), 2359296 elems, 576 tiles ----
  k_make_keys<<<9216, 256, 0, stream>>>(mem_logits, kA, addr, NUM_EL);
  const u32* ki[4] = {kA, kB, kA, kB};
  const u32* vi[4] = {addr, vB, addr, vB};
  u32* ko[4] = {kB, kA, kB, kA};
  u32* vo[4] = {vB, addr, vB, addr};
  for (int p = 0; p < 4; p++) {
    k_hist<<<576, 256, 0, stream>>>(ki[p], counts, p * 8, 576);
    k_scan_par<<<256, 256, 0, stream>>>(counts, pos, 576);
    k_scatter<<<576, 256, 0, stream>>>(ki[p], vi[p], ko[p], vo[p], pos, p * 8, 576);
  }
  // final vals land in addr after pass 3

  // ---- convs + scatter into memf (overwrites sort scratch; addr preserved) ----
  k_conv_scatter<<<4096, 256, 0, stream>>>(addr, cw0, cb0, memf, 1024, 1024, 10, 0);
  k_conv_scatter<<<4096, 256, 0, stream>>>(addr, cw1, cb1, memf, 1024, 1024, 10, OFF1);
  k_conv_scatter<<<1024, 256, 0, stream>>>(addr, cw2, cb2, memf, 512, 512, 9, OFF2);

  // ---- mem conv (8->16) fused with 4x4 adaptive pool ----
  k_wt<<<5, 256, 0, stream>>>(mw, wt);
  k_memconv<<<9216, 256, 0, stream>>>(memf, wt, mbb, partials);
  k_pool_final<<<256, 256, 0, stream>>>(partials, flat);

  // ---- projection matvec -> op_logits in d_out[0..N_OPS) ----
  k_matvec<<<2048, 256, 0, stream>>>(pw, pb, flat, out);

  // ---- sort 2: order = stable argsort(op_logits), 262144 elems, 64 tiles ----
  k_make_keys<<<1024, 256, 0, stream>>>(out, k2A, v2A, N_OPS);
  const u32* ki2[4] = {k2A, k2B, k2A, k2B};
  const u32* vi2[4] = {v2A, v2B, v2A, v2B};
  u32* ko2[4] = {k2B, k2A, k2B, k2A};
  u32* vo2[4] = {v2B, v2A, v2B, v2A};
  for (int p = 0; p < 4; p++) {
    k_hist<<<64, 256, 0, stream>>>(ki2[p], counts, p * 8, 64);
    k_scan_par<<<256, 256, 0, stream>>>(counts, pos, 64);
    k_scatter<<<64, 256, 0, stream>>>(ki2[p], vi2[p], ko2[p], vo2[p], pos, p * 8, 64);
  }
  // order in v2A

  // ---- penalties ----
  k_penalty<<<1024, 256, 0, stream>>>(v2A, addr, pen);
  k_finalize<<<1, 64, 0, stream>>>(pen, out);
}

// Round 3
// 1090.640 us; speedup vs baseline: 1.3501x; 1.0361x over previous
//
#include <hip/hip_runtime.h>
#include <cstdint>
#include <cstddef>

typedef unsigned int u32;
typedef unsigned short u16;
typedef unsigned long long u64;

#define NUM_EL 2359296
#define N_ROWS 294912
#define N_OPS  262144
#define OFF1   1048576
#define OFF2   2097152

// ---------------- workspace layout (bytes) ----------------
// addr:   [0, 9437184)                u32[NUM_EL]
// memf:   [9437184, 47185920)         bf16[NUM_EL*8] (37.75MB; sort scratch lives here first)
//   kA = +0, kB = +9437184, vB = +18874368   (sort1 scratch; vA = addr)
//   k2A= +0, k2B= +1MB, v2A= +2MB, v2B= +3MB (sort2 scratch, memf dead by then)
// counts: [47185920, 47775744)        u32[256*576]
// pos:    [47775744, 48365568)        u32[256*576]
// part:   [48365568, 50724864)        float[64*9216]
// flat:   [50724864, 50725888)        float[256]
// wt:     [50725888, 50730496)        float[1152]
// ppart:  [50730496, 50746880)        double[2*1024]
// ops:    [50746880, 54941184)        float4[N_OPS]  (16B aligned)
#define OFF_MEM    9437184ull
#define OFF_COUNTS 47185920ull
#define OFF_POS    47775744ull
#define OFF_PART   48365568ull
#define OFF_FLAT   50724864ull
#define OFF_WT     50725888ull
#define OFF_PPART  50730496ull
#define OFF_OPS    50746880ull

__device__ inline u32 pk_bf16(float a, float b) {  // RNE pack of 2 floats -> 2 bf16
  u32 ua = __float_as_uint(a), ub = __float_as_uint(b);
  ua = (ua + 0x7fffu + ((ua >> 16) & 1u)) >> 16;
  ub = (ub + 0x7fffu + ((ub >> 16) & 1u)) >> 16;
  return ua | (ub << 16);
}

// fused front: sort1 key-gen (blocks 0..9215) + weight transpose (block 9216)
__global__ __launch_bounds__(256) void k_front(const float* __restrict__ x,
                                               u32* __restrict__ keys, u32* __restrict__ vals,
                                               const float* __restrict__ mw, float* __restrict__ wt) {
  if (blockIdx.x < 9216) {
    int i = blockIdx.x * 256 + threadIdx.x;
    u32 u = __float_as_uint(x[i]);
    u = (u & 0x80000000u) ? ~u : (u | 0x80000000u);
    keys[i] = u;
    vals[i] = (u32)i;
  } else {
    for (int i = threadIdx.x; i < 1152; i += 256) {
      int oc = i & 15;
      int rest = i >> 4;
      int ic = rest & 7;
      int p = rest >> 3;
      int dr = p / 3, dl = p % 3;
      wt[i] = mw[((oc * 8 + ic) * 3 + dr) * 3 + dl];
    }
  }
}

__global__ __launch_bounds__(256) void k_make_keys(const float* __restrict__ x,
                                                   u32* __restrict__ keys,
                                                   u32* __restrict__ vals, int n) {
  int i = blockIdx.x * 256 + threadIdx.x;
  if (i < n) {
    u32 u = __float_as_uint(x[i]);
    u = (u & 0x80000000u) ? ~u : (u | 0x80000000u);
    keys[i] = u;
    vals[i] = (u32)i;
  }
}

// per-block 256-bucket histogram; tile = 4096 elements
__global__ __launch_bounds__(256) void k_hist(const u32* __restrict__ keys,
                                              u32* __restrict__ counts, int shift, int nB) {
  __shared__ u32 h[256];
  int t = threadIdx.x;
  h[t] = 0;
  __syncthreads();
  int base = blockIdx.x * 4096;
#pragma unroll
  for (int k = 0; k < 16; k++) {
    u32 d = (keys[base + t + k * 256] >> shift) & 255u;
    atomicAdd(&h[d], 1u);
  }
  __syncthreads();
  counts[t * nB + blockIdx.x] = h[t];  // digit-major
}

// 256 blocks (one per digit): base = sum counts[0, d*nB), then row scan in LDS.
__global__ __launch_bounds__(256) void k_scan_par(const u32* __restrict__ counts,
                                                  u32* __restrict__ pos, int nB) {
  int d = blockIdx.x, t = threadIdx.x;
  __shared__ u32 red[256];
  u32 s = 0;
  u32 lim = (u32)(d * nB);
  for (u32 i = t; i < lim; i += 256) s += counts[i];
  red[t] = s;
  __syncthreads();
  for (int off = 128; off > 0; off >>= 1) {
    if (t < off) red[t] += red[t + off];
    __syncthreads();
  }
  u32 base = red[0];
  __syncthreads();
  int chunk = (nB + 255) / 256;
  int i0 = t * chunk;
  u32 loc[4];
  u32 lsum = 0;
#pragma unroll 4
  for (int k = 0; k < chunk; k++) {
    int i = i0 + k;
    u32 v = (i < nB) ? counts[d * nB + i] : 0u;
    loc[k] = lsum;
    lsum += v;
  }
  red[t] = lsum;
  __syncthreads();
  for (int off = 1; off < 256; off <<= 1) {
    u32 y = (t >= off) ? red[t - off] : 0u;
    __syncthreads();
    red[t] += y;
    __syncthreads();
  }
  u32 excl = red[t] - lsum;
#pragma unroll 4
  for (int k = 0; k < chunk; k++) {
    int i = i0 + k;
    if (i < nB) pos[d * nB + i] = base + excl + loc[k];
  }
}

// stable scatter: wave owns contiguous 1024-elem region, 16 rounds of 64
__global__ __launch_bounds__(256) void k_scatter(const u32* __restrict__ kin, const u32* __restrict__ vin,
                                                 u32* __restrict__ kout, u32* __restrict__ vout,
                                                 const u32* __restrict__ gbase, int shift, int nB) {
  __shared__ u32 skeys[4096], svals[4096];
  __shared__ u32 whist[4][256];
  __shared__ u32 sbase[256];
  int t = threadIdx.x, b = blockIdx.x;
  int base = b * 4096;
#pragma unroll
  for (int k = 0; k < 16; k++) {
    int idx = t + k * 256;
    skeys[idx] = kin[base + idx];
    svals[idx] = vin[base + idx];
  }
#pragma unroll
  for (int w = 0; w < 4; w++) whist[w][t] = 0;
  sbase[t] = gbase[t * nB + b];
  __syncthreads();
  int w = t >> 6, lane = t & 63;
  u64 lowmask = (1ull << lane) - 1ull;
  u32 dig[16], rnk[16];
#pragma unroll
  for (int j = 0; j < 16; j++) {
    int idx = w * 1024 + j * 64 + lane;
    u32 d = (skeys[idx] >> shift) & 255u;
    u64 m = ~0ull;
#pragma unroll
    for (int bit = 0; bit < 8; bit++) {
      u64 bal = __ballot((d >> bit) & 1u);
      m &= ((d >> bit) & 1u) ? bal : ~bal;
    }
    u32 rr = (u32)__popcll(m & lowmask);
    u32 cnt = (u32)__popcll(m);
    u32 prev = whist[w][d];
    if (rr == 0) whist[w][d] = prev + cnt;
    dig[j] = d;
    rnk[j] = prev + rr;
  }
  __syncthreads();
  {
    u32 s = 0;
    for (int ww = 0; ww < 4; ww++) { u32 v = whist[ww][t]; whist[ww][t] = s; s += v; }
  }
  __syncthreads();
#pragma unroll
  for (int j = 0; j < 16; j++) {
    int idx = w * 1024 + j * 64 + lane;
    u32 d = dig[j];
    u32 p = sbase[d] + whist[w][d] + rnk[j];
    kout[p] = skeys[idx];
    vout[p] = svals[idx];
  }
}

// last sort2 pass: instead of (key,val), write A-table row float4(A0,A1,A2,0) at sorted pos
__global__ __launch_bounds__(256) void k_scatter_ops(const u32* __restrict__ kin, const u32* __restrict__ vin,
                                                     const u32* __restrict__ gbase, int shift, int nB,
                                                     const u32* __restrict__ addr, float4* __restrict__ ops) {
  __shared__ u32 skeys[4096], svals[4096];
  __shared__ u32 whist[4][256];
  __shared__ u32 sbase[256];
  int t = threadIdx.x, b = blockIdx.x;
  int base = b * 4096;
#pragma unroll
  for (int k = 0; k < 16; k++) {
    int idx = t + k * 256;
    skeys[idx] = kin[base + idx];
    svals[idx] = vin[base + idx];
  }
#pragma unroll
  for (int w = 0; w < 4; w++) whist[w][t] = 0;
  sbase[t] = gbase[t * nB + b];
  __syncthreads();
  int w = t >> 6, lane = t & 63;
  u64 lowmask = (1ull << lane) - 1ull;
  u32 dig[16], rnk[16];
#pragma unroll
  for (int j = 0; j < 16; j++) {
    int idx = w * 1024 + j * 64 + lane;
    u32 d = (skeys[idx] >> shift) & 255u;
    u64 m = ~0ull;
#pragma unroll
    for (int bit = 0; bit < 8; bit++) {
      u64 bal = __ballot((d >> bit) & 1u);
      m &= ((d >> bit) & 1u) ? bal : ~bal;
    }
    u32 rr = (u32)__popcll(m & lowmask);
    u32 cnt = (u32)__popcll(m);
    u32 prev = whist[w][d];
    if (rr == 0) whist[w][d] = prev + cnt;
    dig[j] = d;
    rnk[j] = prev + rr;
  }
  __syncthreads();
  {
    u32 s = 0;
    for (int ww = 0; ww < 4; ww++) { u32 v = whist[ww][t]; whist[ww][t] = s; s += v; }
  }
  __syncthreads();
#pragma unroll
  for (int j = 0; j < 16; j++) {
    int idx = w * 1024 + j * 64 + lane;
    u32 d = dig[j];
    u32 p = sbase[d] + whist[w][d] + rnk[j];
    u32 r = svals[idx];
    int i = (int)(r >> 9), jj = (int)(r & 511);
    float A0 = (float)addr[(i << 10) + jj];
    float A1 = (float)addr[OFF1 + (i << 10) + jj];
    float A2 = (float)addr[OFF2 + (int)r];
    ops[p] = make_float4(A0, A1, A2, 0.0f);
  }
}

// 1->8ch 3x3 SAME conv on addr-as-float image, relu, scatter bf16x8 to memfh[addr*8]
__global__ __launch_bounds__(256) void k_conv_scatter(const u32* __restrict__ addr,
                                                      const float* __restrict__ cw,
                                                      const float* __restrict__ cb,
                                                      u16* __restrict__ memfh,
                                                      int H, int W, int lw, int off) {
  int pix = blockIdx.x * 256 + threadIdx.x;
  int i = pix >> lw, j = pix & (W - 1);
  float x[3][3];
#pragma unroll
  for (int dr = 0; dr < 3; dr++)
#pragma unroll
    for (int dc = 0; dc < 3; dc++) {
      int r = i + dr - 1, c = j + dc - 1;
      bool inb = ((unsigned)r < (unsigned)H) && ((unsigned)c < (unsigned)W);
      x[dr][dc] = inb ? (float)addr[off + r * W + c] : 0.0f;
    }
  u32 a = addr[off + pix];
  float acc[8];
#pragma unroll
  for (int oc = 0; oc < 8; oc++) {
    float s = cb[oc];
#pragma unroll
    for (int dr = 0; dr < 3; dr++)
#pragma unroll
      for (int dc = 0; dc < 3; dc++)
        s = fmaf(x[dr][dc], cw[oc * 9 + dr * 3 + dc], s);
    acc[oc] = fmaxf(s, 0.0f);
  }
  uint4 pk;
  pk.x = pk_bf16(acc[0], acc[1]);
  pk.y = pk_bf16(acc[2], acc[3]);
  pk.z = pk_bf16(acc[4], acc[5]);
  pk.w = pk_bf16(acc[6], acc[7]);
  *(uint4*)(memfh + (size_t)a * 8) = pk;
}

// 8->16ch 3x3 conv on [N_ROWS x 8] bf16 channel-last, relu, fused 4x4 pool partials
__global__ __launch_bounds__(256) void k_memconv(const u16* __restrict__ memfh,
                                                 const float* __restrict__ wt,
                                                 const float* __restrict__ mb,
                                                 float* __restrict__ partials) {
  __shared__ float tile[34 * 80];
  __shared__ float pool_s[256 * 17];
  int t = threadIdx.x;
  int r0 = blockIdx.x * 32;
  for (int idx = t; idx < 34 * 8; idx += 256) {     // 8 groups of 8 bf16 per row
    int rr = idx >> 3, g = idx & 7;
    int r = r0 - 1 + rr;
    float f[8];
    if ((unsigned)r < (unsigned)N_ROWS) {
      uint4 u = *(const uint4*)(memfh + (size_t)r * 64 + g * 8);
      f[0] = __uint_as_float(u.x << 16); f[1] = __uint_as_float(u.x & 0xffff0000u);
      f[2] = __uint_as_float(u.y << 16); f[3] = __uint_as_float(u.y & 0xffff0000u);
      f[4] = __uint_as_float(u.z << 16); f[5] = __uint_as_float(u.z & 0xffff0000u);
      f[6] = __uint_as_float(u.w << 16); f[7] = __uint_as_float(u.w & 0xffff0000u);
    } else {
#pragma unroll
      for (int c = 0; c < 8; c++) f[c] = 0.0f;
    }
#pragma unroll
    for (int c = 0; c < 8; c++) tile[rr * 80 + (g + 1) * 8 + c] = f[c];
  }
  for (int idx = t; idx < 34 * 16; idx += 256) {
    int rr = idx >> 4, k = idx & 15;
    int col = (k < 8) ? k : (64 + k);
    tile[rr * 80 + col] = 0.0f;
  }
  __syncthreads();
  int lr = t >> 3, l = t & 7;
  float acc[16];
#pragma unroll
  for (int oc = 0; oc < 16; oc++) acc[oc] = mb[oc];
#pragma unroll
  for (int dr = 0; dr < 3; dr++) {
#pragma unroll
    for (int dl = 0; dl < 3; dl++) {
      const float* src = &tile[(lr + dr) * 80 + (l + dl) * 8];
      float4 a0 = *(const float4*)(src);
      float4 a1 = *(const float4*)(src + 4);
      float xv[8] = {a0.x, a0.y, a0.z, a0.w, a1.x, a1.y, a1.z, a1.w};
      const float* wp = &wt[(dr * 3 + dl) * 128];
#pragma unroll
      for (int ic = 0; ic < 8; ic++) {
#pragma unroll
        for (int oc = 0; oc < 16; oc++)
          acc[oc] = fmaf(xv[ic], wp[ic * 16 + oc], acc[oc]);
      }
    }
  }
#pragma unroll
  for (int oc = 0; oc < 16; oc++) pool_s[t * 17 + oc] = fmaxf(acc[oc], 0.0f);
  __syncthreads();
  if (t < 64) {
    int oc = t >> 2, lb = t & 3;
    float s = 0.0f;
    for (int lr2 = 0; lr2 < 32; lr2++) {
      int t2 = lr2 * 8 + lb * 2;
      s += pool_s[t2 * 17 + oc] + pool_s[(t2 + 1) * 17 + oc];
    }
    partials[(size_t)(oc * 4 + lb) * 9216 + blockIdx.x] = s;
  }
}

__global__ __launch_bounds__(256) void k_pool_final(const float* __restrict__ partials,
                                                    float* __restrict__ flat) {
  int f = blockIdx.x;
  int oc = f >> 4, rb = (f >> 2) & 3, lb = f & 3;
  const float* src = partials + (size_t)(oc * 4 + lb) * 9216 + rb * 2304;
  double s = 0.0;
  for (int i = threadIdx.x; i < 2304; i += 256) s += (double)src[i];
  __shared__ double sd[256];
  sd[threadIdx.x] = s;
  __syncthreads();
  for (int off = 128; off > 0; off >>= 1) {
    if (threadIdx.x < off) sd[threadIdx.x] += sd[threadIdx.x + off];
    __syncthreads();
  }
  if (threadIdx.x == 0) flat[f] = (float)(sd[0] * (1.0 / 147456.0));
}

// one wave per 32 rows of proj_w [N_OPS][256]; 2-row unroll for MLP
__global__ __launch_bounds__(256) void k_matvec(const float* __restrict__ pw,
                                                const float* __restrict__ pb,
                                                const float* __restrict__ flat,
                                                float* __restrict__ out) {
  int t = threadIdx.x;
  int lane = t & 63;
  int g = (blockIdx.x * 256 + t) >> 6;
  float4 f4 = ((const float4*)flat)[lane];
  int row0 = g * 32;
  for (int it = 0; it < 32; it += 2) {
    int row = row0 + it;
    float4 wa = ((const float4*)(pw + (size_t)row * 256))[lane];
    float4 wb = ((const float4*)(pw + (size_t)(row + 1) * 256))[lane];
    float sa = wa.x * f4.x + wa.y * f4.y + wa.z * f4.z + wa.w * f4.w;
    float sb = wb.x * f4.x + wb.y * f4.y + wb.z * f4.z + wb.w * f4.w;
#pragma unroll
    for (int off = 32; off > 0; off >>= 1) {
      sa += __shfl_xor(sa, off, 64);
      sb += __shfl_xor(sb, off, 64);
    }
    if (lane == 0) {
      out[row] = sa + pb[row];
      out[row + 1] = sb + pb[row + 1];
    }
  }
}

__device__ inline double staged_pair(float x) {
  float h = fabsf(x);
  double mult = (h <= 2.f) ? 1.0 : (h <= 4.f) ? 1.5 : (h <= 8.f) ? 2.0 : (h <= 16.f) ? 3.0 : 5.0;
  double hh = (double)h;
  if (x > 0.f) return hh * mult;
  if (x < 0.f) return hh * hh * mult;
  return 0.0;
}

// coalesced: ops[k] = (A0,A1,A2); per-block partials, NO global atomics
__global__ __launch_bounds__(256) void k_penalty(const float4* __restrict__ ops,
                                                 double* __restrict__ ppart) {
  int k = blockIdx.x * 256 + threadIdx.x;
  float4 a = ops[k];
  double intra = staged_pair(a.y - a.x) + staged_pair(a.z - a.y);
  double inter = 0.0;
  if (k < N_OPS - 1) {
    float4 b = ops[k + 1];
    inter = staged_pair(b.x - a.z);
  }
  __shared__ double s0[256], s1[256];
  s0[threadIdx.x] = inter;
  s1[threadIdx.x] = intra;
  __syncthreads();
  for (int off = 128; off > 0; off >>= 1) {
    if (threadIdx.x < off) {
      s0[threadIdx.x] += s0[threadIdx.x + off];
      s1[threadIdx.x] += s1[threadIdx.x + off];
    }
    __syncthreads();
  }
  if (threadIdx.x == 0) {
    ppart[blockIdx.x] = s0[0];
    ppart[1024 + blockIdx.x] = s1[0];
  }
}

__global__ __launch_bounds__(256) void k_finalize(const double* __restrict__ ppart,
                                                  float* __restrict__ out) {
  int t = threadIdx.x;
  double s0 = 0.0, s1 = 0.0;
  for (int i = t; i < 1024; i += 256) {
    s0 += ppart[i];
    s1 += ppart[1024 + i];
  }
  __shared__ double a0[256], a1[256];
  a0[t] = s0;
  a1[t] = s1;
  __syncthreads();
  for (int off = 128; off > 0; off >>= 1) {
    if (t < off) {
      a0[t] += a0[t + off];
      a1[t] += a1[t + off];
    }
    __syncthreads();
  }
  if (t == 0) {
    out[N_OPS] = (float)a0[0];
    out[N_OPS + 1] = (float)a1[0];
  }
}

extern "C" void kernel_launch(void* const* d_in, const int* in_sizes, int n_in,
                              void* d_out, int out_size, void* d_ws, size_t ws_size,
                              hipStream_t stream) {
  const float* mem_logits = (const float*)d_in[0];
  const float* cw0 = (const float*)d_in[1];
  const float* cb0 = (const float*)d_in[2];
  const float* cw1 = (const float*)d_in[3];
  const float* cb1 = (const float*)d_in[4];
  const float* cw2 = (const float*)d_in[5];
  const float* cb2 = (const float*)d_in[6];
  const float* mw  = (const float*)d_in[7];
  const float* mbb = (const float*)d_in[8];
  const float* pw  = (const float*)d_in[9];
  const float* pb  = (const float*)d_in[10];
  float* out = (float*)d_out;
  char* ws = (char*)d_ws;

  u32* addr      = (u32*)(ws);
  u16* memfh     = (u16*)(ws + OFF_MEM);
  u32* kA        = (u32*)(ws + OFF_MEM);
  u32* kB        = (u32*)(ws + OFF_MEM + 9437184ull);
  u32* vB        = (u32*)(ws + OFF_MEM + 18874368ull);
  u32* counts    = (u32*)(ws + OFF_COUNTS);
  u32* pos       = (u32*)(ws + OFF_POS);
  float* partials= (float*)(ws + OFF_PART);
  float* flat    = (float*)(ws + OFF_FLAT);
  float* wt      = (float*)(ws + OFF_WT);
  double* ppart  = (double*)(ws + OFF_PPART);
  float4* ops    = (float4*)(ws + OFF_OPS);
  u32* k2A       = (u32*)(ws + OFF_MEM);
  u32* k2B       = (u32*)(ws + OFF_MEM + 1048576ull);
  u32* v2A       = (u32*)(ws + OFF_MEM + 2097152ull);
  u32* v2B       = (u32*)(ws + OFF_MEM + 3145728ull);

  // ---- sort 1 key-gen + weight transpose (fused) ----
  k_front<<<9217, 256, 0, stream>>>(mem_logits, kA, addr, mw, wt);
  const u32* ki[4] = {kA, kB, kA, kB};
  const u32* vi[4] = {addr, vB, addr, vB};
  u32* ko[4] = {kB, kA, kB, kA};
  u32* vo[4] = {vB, addr, vB, addr};
  for (int p = 0; p < 4; p++) {
    k_hist<<<576, 256, 0, stream>>>(ki[p], counts, p * 8, 576);
    k_scan_par<<<256, 256, 0, stream>>>(counts, pos, 576);
    k_scatter<<<576, 256, 0, stream>>>(ki[p], vi[p], ko[p], vo[p], pos, p * 8, 576);
  }
  // final vals land in addr

  // ---- convs + bf16 scatter into memfh ----
  k_conv_scatter<<<4096, 256, 0, stream>>>(addr, cw0, cb0, memfh, 1024, 1024, 10, 0);
  k_conv_scatter<<<4096, 256, 0, stream>>>(addr, cw1, cb1, memfh, 1024, 1024, 10, OFF1);
  k_conv_scatter<<<1024, 256, 0, stream>>>(addr, cw2, cb2, memfh, 512, 512, 9, OFF2);

  // ---- mem conv (8->16) fused with 4x4 adaptive pool ----
  k_memconv<<<9216, 256, 0, stream>>>(memfh, wt, mbb, partials);
  k_pool_final<<<256, 256, 0, stream>>>(partials, flat);

  // ---- projection matvec -> op_logits ----
  k_matvec<<<2048, 256, 0, stream>>>(pw, pb, flat, out);

  // ---- sort 2 (memf dead now); last pass writes A-table in sorted order ----
  k_make_keys<<<1024, 256, 0, stream>>>(out, k2A, v2A, N_OPS);
  const u32* ki2[3] = {k2A, k2B, k2A};
  const u32* vi2[3] = {v2A, v2B, v2A};
  u32* ko2[3] = {k2B, k2A, k2B};
  u32* vo2[3] = {v2B, v2A, v2B};
  for (int p = 0; p < 3; p++) {
    k_hist<<<64, 256, 0, stream>>>(ki2[p], counts, p * 8, 64);
    k_scan_par<<<256, 256, 0, stream>>>(counts, pos, 64);
    k_scatter<<<64, 256, 0, stream>>>(ki2[p], vi2[p], ko2[p], vo2[p], pos, p * 8, 64);
  }
  k_hist<<<64, 256, 0, stream>>>(k2B, counts, 24, 64);
  k_scan_par<<<256, 256, 0, stream>>>(counts, pos, 64);
  k_scatter_ops<<<64, 256, 0, stream>>>(k2B, v2B, pos, 24, 64, addr, ops);

  // ---- penalties (no atomics) ----
  k_penalty<<<1024, 256, 0, stream>>>(ops, ppart);
  k_finalize<<<1, 256, 0, stream>>>(ppart, out);
}

// Round 4
// 1030.257 us; speedup vs baseline: 1.4293x; 1.0586x over previous
//
#include <hip/hip_runtime.h>
#include <cstdint>
#include <cstddef>

typedef unsigned int u32;
typedef unsigned short u16;
typedef unsigned long long u64;

#define NUM_EL 2359296
#define N_ROWS 294912
#define N_OPS  262144
#define OFF1   1048576
#define OFF2   2097152

// ---------------- workspace layout (bytes) ----------------
// addr:   [0, 9437184)                u32[NUM_EL]
// memf:   [9437184, 47185920)         bf16[NUM_EL*8] (37.75MB; sort scratch lives here first)
//   kA = +0, kB = +9437184, vB = +18874368   (sort1 scratch; vA = addr)
//   k2A= +0, k2B= +1MB, v2A= +2MB, v2B= +3MB (sort2 scratch, memf dead by then)
// counts: [47185920, 47775744)        u32[256*576]
// pos:    [47775744, 48365568)        u32[256*576]
// part:   [48365568, 50724864)        float[64*9216]
// flat:   [50724864, 50725888)        float[256]
// wt:     [50725888, 50730496)        float[1152]
// ppart:  [50730496, 50746880)        double[2*1024]
// ops:    [50746880, 54941184)        float4[N_OPS]
#define OFF_MEM    9437184ull
#define OFF_COUNTS 47185920ull
#define OFF_POS    47775744ull
#define OFF_PART   48365568ull
#define OFF_FLAT   50724864ull
#define OFF_WT     50725888ull
#define OFF_PPART  50730496ull
#define OFF_OPS    50746880ull

__device__ inline u32 pk_bf16(float a, float b) {  // RNE pack of 2 floats -> 2 bf16
  u32 ua = __float_as_uint(a), ub = __float_as_uint(b);
  ua = (ua + 0x7fffu + ((ua >> 16) & 1u)) >> 16;
  ub = (ub + 0x7fffu + ((ub >> 16) & 1u)) >> 16;
  return ua | (ub << 16);
}

// fused front: sort1 key-gen (blocks 0..9215) + weight transpose (block 9216)
__global__ __launch_bounds__(256) void k_front(const float* __restrict__ x,
                                               u32* __restrict__ keys, u32* __restrict__ vals,
                                               const float* __restrict__ mw, float* __restrict__ wt) {
  if (blockIdx.x < 9216) {
    int i = blockIdx.x * 256 + threadIdx.x;
    u32 u = __float_as_uint(x[i]);
    u = (u & 0x80000000u) ? ~u : (u | 0x80000000u);
    keys[i] = u;
    vals[i] = (u32)i;
  } else {
    for (int i = threadIdx.x; i < 1152; i += 256) {
      int oc = i & 15;
      int rest = i >> 4;
      int ic = rest & 7;
      int p = rest >> 3;
      int dr = p / 3, dl = p % 3;
      wt[i] = mw[((oc * 8 + ic) * 3 + dr) * 3 + dl];
    }
  }
}

__global__ __launch_bounds__(256) void k_make_keys(const float* __restrict__ x,
                                                   u32* __restrict__ keys,
                                                   u32* __restrict__ vals, int n) {
  int i = blockIdx.x * 256 + threadIdx.x;
  if (i < n) {
    u32 u = __float_as_uint(x[i]);
    u = (u & 0x80000000u) ? ~u : (u | 0x80000000u);
    keys[i] = u;
    vals[i] = (u32)i;
  }
}

// per-block 256-bucket histogram; tile = 4096 elements
__global__ __launch_bounds__(256) void k_hist(const u32* __restrict__ keys,
                                              u32* __restrict__ counts, int shift, int nB) {
  __shared__ u32 h[256];
  int t = threadIdx.x;
  h[t] = 0;
  __syncthreads();
  int base = blockIdx.x * 4096;
#pragma unroll
  for (int k = 0; k < 16; k++) {
    u32 d = (keys[base + t + k * 256] >> shift) & 255u;
    atomicAdd(&h[d], 1u);
  }
  __syncthreads();
  counts[t * nB + blockIdx.x] = h[t];  // digit-major
}

// 256 blocks (one per digit): base = sum counts[0, d*nB), then row scan in LDS.
__global__ __launch_bounds__(256) void k_scan_par(const u32* __restrict__ counts,
                                                  u32* __restrict__ pos, int nB) {
  int d = blockIdx.x, t = threadIdx.x;
  __shared__ u32 red[256];
  u32 s = 0;
  u32 lim = (u32)(d * nB);
  for (u32 i = t; i < lim; i += 256) s += counts[i];
  red[t] = s;
  __syncthreads();
  for (int off = 128; off > 0; off >>= 1) {
    if (t < off) red[t] += red[t + off];
    __syncthreads();
  }
  u32 base = red[0];
  __syncthreads();
  int chunk = (nB + 255) / 256;
  int i0 = t * chunk;
  u32 loc[4];
  u32 lsum = 0;
#pragma unroll 4
  for (int k = 0; k < chunk; k++) {
    int i = i0 + k;
    u32 v = (i < nB) ? counts[d * nB + i] : 0u;
    loc[k] = lsum;
    lsum += v;
  }
  red[t] = lsum;
  __syncthreads();
  for (int off = 1; off < 256; off <<= 1) {
    u32 y = (t >= off) ? red[t - off] : 0u;
    __syncthreads();
    red[t] += y;
    __syncthreads();
  }
  u32 excl = red[t] - lsum;
#pragma unroll 4
  for (int k = 0; k < chunk; k++) {
    int i = i0 + k;
    if (i < nB) pos[d * nB + i] = base + excl + loc[k];
  }
}

// Stable scatter with LDS reorder-by-digit: global writes become coalesced
// runs (~16 elems/digit/block) instead of random 4B scatters.
// Wave w owns region [w*1024,(w+1)*1024), loads straight global->regs.
__global__ __launch_bounds__(256) void k_scatter(const u32* __restrict__ kin, const u32* __restrict__ vin,
                                                 u32* __restrict__ kout, u32* __restrict__ vout,
                                                 const u32* __restrict__ gbase, int shift, int nB,
                                                 int write_keys) {
  __shared__ u32 sk[4096], sv[4096];
  __shared__ u32 whist[4][256];
  __shared__ u32 sbase[256], lstart[256], gdelta[256], red[256];
  int t = threadIdx.x, b = blockIdx.x;
  int base = b * 4096;
#pragma unroll
  for (int w2 = 0; w2 < 4; w2++) whist[w2][t] = 0;
  sbase[t] = gbase[t * nB + b];
  __syncthreads();
  int w = t >> 6, lane = t & 63;
  u64 lowmask = (1ull << lane) - 1ull;
  u32 kk[16], vv[16], dig[16], rnk[16];
#pragma unroll
  for (int j = 0; j < 16; j++) {
    int idx = base + w * 1024 + j * 64 + lane;
    kk[j] = kin[idx];
    vv[j] = vin[idx];
  }
#pragma unroll
  for (int j = 0; j < 16; j++) {
    u32 d = (kk[j] >> shift) & 255u;
    u64 m = ~0ull;
#pragma unroll
    for (int bit = 0; bit < 8; bit++) {
      u64 bal = __ballot((d >> bit) & 1u);
      m &= ((d >> bit) & 1u) ? bal : ~bal;
    }
    u32 rr = (u32)__popcll(m & lowmask);
    u32 cnt = (u32)__popcll(m);
    u32 prev = whist[w][d];        // wave-synchronous LDS read
    if (rr == 0) whist[w][d] = prev + cnt;
    dig[j] = d;
    rnk[j] = prev + rr;
  }
  __syncthreads();
  // thread t = digit t: cross-wave offsets + block-local digit starts
  {
    u32 s0 = whist[0][t], s1 = whist[1][t], s2 = whist[2][t], s3 = whist[3][t];
    u32 tot = s0 + s1 + s2 + s3;
    whist[0][t] = 0; whist[1][t] = s0; whist[2][t] = s0 + s1; whist[3][t] = s0 + s1 + s2;
    red[t] = tot;
    __syncthreads();
    for (int off = 1; off < 256; off <<= 1) {
      u32 y = (t >= off) ? red[t - off] : 0u;
      __syncthreads();
      red[t] += y;
      __syncthreads();
    }
    u32 lst = red[t] - tot;
    lstart[t] = lst;
    gdelta[t] = sbase[t] - lst;
  }
  __syncthreads();
#pragma unroll
  for (int j = 0; j < 16; j++) {
    u32 d = dig[j];
    u32 lpos = lstart[d] + whist[w][d] + rnk[j];
    sk[lpos] = kk[j];
    sv[lpos] = vv[j];
  }
  __syncthreads();
#pragma unroll
  for (int r = 0; r < 16; r++) {
    int idx = t + r * 256;
    u32 key = sk[idx];
    u32 d = (key >> shift) & 255u;
    u32 gpos = gdelta[d] + (u32)idx;
    vout[gpos] = sv[idx];
    if (write_keys) kout[gpos] = key;
  }
}

// last sort2 pass: LDS reorder, then write A-table row float4(A0,A1,A2,0) at sorted pos
__global__ __launch_bounds__(256) void k_scatter_ops(const u32* __restrict__ kin, const u32* __restrict__ vin,
                                                     const u32* __restrict__ gbase, int shift, int nB,
                                                     const u32* __restrict__ addr, float4* __restrict__ ops) {
  __shared__ u32 sk[4096], sv[4096];
  __shared__ u32 whist[4][256];
  __shared__ u32 sbase[256], lstart[256], gdelta[256], red[256];
  int t = threadIdx.x, b = blockIdx.x;
  int base = b * 4096;
#pragma unroll
  for (int w2 = 0; w2 < 4; w2++) whist[w2][t] = 0;
  sbase[t] = gbase[t * nB + b];
  __syncthreads();
  int w = t >> 6, lane = t & 63;
  u64 lowmask = (1ull << lane) - 1ull;
  u32 kk[16], vv[16], dig[16], rnk[16];
#pragma unroll
  for (int j = 0; j < 16; j++) {
    int idx = base + w * 1024 + j * 64 + lane;
    kk[j] = kin[idx];
    vv[j] = vin[idx];
  }
#pragma unroll
  for (int j = 0; j < 16; j++) {
    u32 d = (kk[j] >> shift) & 255u;
    u64 m = ~0ull;
#pragma unroll
    for (int bit = 0; bit < 8; bit++) {
      u64 bal = __ballot((d >> bit) & 1u);
      m &= ((d >> bit) & 1u) ? bal : ~bal;
    }
    u32 rr = (u32)__popcll(m & lowmask);
    u32 cnt = (u32)__popcll(m);
    u32 prev = whist[w][d];
    if (rr == 0) whist[w][d] = prev + cnt;
    dig[j] = d;
    rnk[j] = prev + rr;
  }
  __syncthreads();
  {
    u32 s0 = whist[0][t], s1 = whist[1][t], s2 = whist[2][t], s3 = whist[3][t];
    u32 tot = s0 + s1 + s2 + s3;
    whist[0][t] = 0; whist[1][t] = s0; whist[2][t] = s0 + s1; whist[3][t] = s0 + s1 + s2;
    red[t] = tot;
    __syncthreads();
    for (int off = 1; off < 256; off <<= 1) {
      u32 y = (t >= off) ? red[t - off] : 0u;
      __syncthreads();
      red[t] += y;
      __syncthreads();
    }
    u32 lst = red[t] - tot;
    lstart[t] = lst;
    gdelta[t] = sbase[t] - lst;
  }
  __syncthreads();
#pragma unroll
  for (int j = 0; j < 16; j++) {
    u32 d = dig[j];
    u32 lpos = lstart[d] + whist[w][d] + rnk[j];
    sk[lpos] = kk[j];
    sv[lpos] = vv[j];
  }
  __syncthreads();
#pragma unroll
  for (int r = 0; r < 16; r++) {
    int idx = t + r * 256;
    u32 key = sk[idx];
    u32 d = (key >> shift) & 255u;
    u32 gpos = gdelta[d] + (u32)idx;
    u32 rv = sv[idx];
    int i = (int)(rv >> 9), jj = (int)(rv & 511);
    float A0 = (float)addr[(i << 10) + jj];
    float A1 = (float)addr[OFF1 + (i << 10) + jj];
    float A2 = (float)addr[OFF2 + (int)rv];
    ops[gpos] = make_float4(A0, A1, A2, 0.0f);
  }
}

// 1->8ch 3x3 SAME conv on addr-as-float image, relu, scatter bf16x8 to memfh[addr*8]
__global__ __launch_bounds__(256) void k_conv_scatter(const u32* __restrict__ addr,
                                                      const float* __restrict__ cw,
                                                      const float* __restrict__ cb,
                                                      u16* __restrict__ memfh,
                                                      int H, int W, int lw, int off) {
  int pix = blockIdx.x * 256 + threadIdx.x;
  int i = pix >> lw, j = pix & (W - 1);
  float x[3][3];
#pragma unroll
  for (int dr = 0; dr < 3; dr++)
#pragma unroll
    for (int dc = 0; dc < 3; dc++) {
      int r = i + dr - 1, c = j + dc - 1;
      bool inb = ((unsigned)r < (unsigned)H) && ((unsigned)c < (unsigned)W);
      x[dr][dc] = inb ? (float)addr[off + r * W + c] : 0.0f;
    }
  u32 a = addr[off + pix];
  float acc[8];
#pragma unroll
  for (int oc = 0; oc < 8; oc++) {
    float s = cb[oc];
#pragma unroll
    for (int dr = 0; dr < 3; dr++)
#pragma unroll
      for (int dc = 0; dc < 3; dc++)
        s = fmaf(x[dr][dc], cw[oc * 9 + dr * 3 + dc], s);
    acc[oc] = fmaxf(s, 0.0f);
  }
  uint4 pk;
  pk.x = pk_bf16(acc[0], acc[1]);
  pk.y = pk_bf16(acc[2], acc[3]);
  pk.z = pk_bf16(acc[4], acc[5]);
  pk.w = pk_bf16(acc[6], acc[7]);
  *(uint4*)(memfh + (size_t)a * 8) = pk;
}

// 8->16ch 3x3 conv on [N_ROWS x 8] bf16 channel-last, relu, fused 4x4 pool partials
__global__ __launch_bounds__(256) void k_memconv(const u16* __restrict__ memfh,
                                                 const float* __restrict__ wt,
                                                 const float* __restrict__ mb,
                                                 float* __restrict__ partials) {
  __shared__ float tile[34 * 80];
  __shared__ float pool_s[256 * 17];
  int t = threadIdx.x;
  int r0 = blockIdx.x * 32;
  for (int idx = t; idx < 34 * 8; idx += 256) {
    int rr = idx >> 3, g = idx & 7;
    int r = r0 - 1 + rr;
    float f[8];
    if ((unsigned)r < (unsigned)N_ROWS) {
      uint4 u = *(const uint4*)(memfh + (size_t)r * 64 + g * 8);
      f[0] = __uint_as_float(u.x << 16); f[1] = __uint_as_float(u.x & 0xffff0000u);
      f[2] = __uint_as_float(u.y << 16); f[3] = __uint_as_float(u.y & 0xffff0000u);
      f[4] = __uint_as_float(u.z << 16); f[5] = __uint_as_float(u.z & 0xffff0000u);
      f[6] = __uint_as_float(u.w << 16); f[7] = __uint_as_float(u.w & 0xffff0000u);
    } else {
#pragma unroll
      for (int c = 0; c < 8; c++) f[c] = 0.0f;
    }
#pragma unroll
    for (int c = 0; c < 8; c++) tile[rr * 80 + (g + 1) * 8 + c] = f[c];
  }
  for (int idx = t; idx < 34 * 16; idx += 256) {
    int rr = idx >> 4, k = idx & 15;
    int col = (k < 8) ? k : (64 + k);
    tile[rr * 80 + col] = 0.0f;
  }
  __syncthreads();
  int lr = t >> 3, l = t & 7;
  float acc[16];
#pragma unroll
  for (int oc = 0; oc < 16; oc++) acc[oc] = mb[oc];
#pragma unroll
  for (int dr = 0; dr < 3; dr++) {
#pragma unroll
    for (int dl = 0; dl < 3; dl++) {
      const float* src = &tile[(lr + dr) * 80 + (l + dl) * 8];
      float4 a0 = *(const float4*)(src);
      float4 a1 = *(const float4*)(src + 4);
      float xv[8] = {a0.x, a0.y, a0.z, a0.w, a1.x, a1.y, a1.z, a1.w};
      const float* wp = &wt[(dr * 3 + dl) * 128];
#pragma unroll
      for (int ic = 0; ic < 8; ic++) {
#pragma unroll
        for (int oc = 0; oc < 16; oc++)
          acc[oc] = fmaf(xv[ic], wp[ic * 16 + oc], acc[oc]);
      }
    }
  }
#pragma unroll
  for (int oc = 0; oc < 16; oc++) pool_s[t * 17 + oc] = fmaxf(acc[oc], 0.0f);
  __syncthreads();
  if (t < 64) {
    int oc = t >> 2, lb = t & 3;
    float s = 0.0f;
    for (int lr2 = 0; lr2 < 32; lr2++) {
      int t2 = lr2 * 8 + lb * 2;
      s += pool_s[t2 * 17 + oc] + pool_s[(t2 + 1) * 17 + oc];
    }
    partials[(size_t)(oc * 4 + lb) * 9216 + blockIdx.x] = s;
  }
}

__global__ __launch_bounds__(256) void k_pool_final(const float* __restrict__ partials,
                                                    float* __restrict__ flat) {
  int f = blockIdx.x;
  int oc = f >> 4, rb = (f >> 2) & 3, lb = f & 3;
  const float* src = partials + (size_t)(oc * 4 + lb) * 9216 + rb * 2304;
  double s = 0.0;
  for (int i = threadIdx.x; i < 2304; i += 256) s += (double)src[i];
  __shared__ double sd[256];
  sd[threadIdx.x] = s;
  __syncthreads();
  for (int off = 128; off > 0; off >>= 1) {
    if (threadIdx.x < off) sd[threadIdx.x] += sd[threadIdx.x + off];
    __syncthreads();
  }
  if (threadIdx.x == 0) flat[f] = (float)(sd[0] * (1.0 / 147456.0));
}

// one wave per 32 rows of proj_w [N_OPS][256]
__global__ __launch_bounds__(256) void k_matvec(const float* __restrict__ pw,
                                                const float* __restrict__ pb,
                                                const float* __restrict__ flat,
                                                float* __restrict__ out) {
  int t = threadIdx.x;
  int lane = t & 63;
  int g = (blockIdx.x * 256 + t) >> 6;
  float4 f4 = ((const float4*)flat)[lane];
  int row0 = g * 32;
  for (int it = 0; it < 32; it += 2) {
    int row = row0 + it;
    float4 wa = ((const float4*)(pw + (size_t)row * 256))[lane];
    float4 wb = ((const float4*)(pw + (size_t)(row + 1) * 256))[lane];
    float sa = wa.x * f4.x + wa.y * f4.y + wa.z * f4.z + wa.w * f4.w;
    float sb = wb.x * f4.x + wb.y * f4.y + wb.z * f4.z + wb.w * f4.w;
#pragma unroll
    for (int off = 32; off > 0; off >>= 1) {
      sa += __shfl_xor(sa, off, 64);
      sb += __shfl_xor(sb, off, 64);
    }
    if (lane == 0) {
      out[row] = sa + pb[row];
      out[row + 1] = sb + pb[row + 1];
    }
  }
}

__device__ inline double staged_pair(float x) {
  float h = fabsf(x);
  double mult = (h <= 2.f) ? 1.0 : (h <= 4.f) ? 1.5 : (h <= 8.f) ? 2.0 : (h <= 16.f) ? 3.0 : 5.0;
  double hh = (double)h;
  if (x > 0.f) return hh * mult;
  if (x < 0.f) return hh * hh * mult;
  return 0.0;
}

// coalesced: ops[k] = (A0,A1,A2); per-block partials, NO global atomics
__global__ __launch_bounds__(256) void k_penalty(const float4* __restrict__ ops,
                                                 double* __restrict__ ppart) {
  int k = blockIdx.x * 256 + threadIdx.x;
  float4 a = ops[k];
  double intra = staged_pair(a.y - a.x) + staged_pair(a.z - a.y);
  double inter = 0.0;
  if (k < N_OPS - 1) {
    float4 b = ops[k + 1];
    inter = staged_pair(b.x - a.z);
  }
  __shared__ double s0[256], s1[256];
  s0[threadIdx.x] = inter;
  s1[threadIdx.x] = intra;
  __syncthreads();
  for (int off = 128; off > 0; off >>= 1) {
    if (threadIdx.x < off) {
      s0[threadIdx.x] += s0[threadIdx.x + off];
      s1[threadIdx.x] += s1[threadIdx.x + off];
    }
    __syncthreads();
  }
  if (threadIdx.x == 0) {
    ppart[blockIdx.x] = s0[0];
    ppart[1024 + blockIdx.x] = s1[0];
  }
}

__global__ __launch_bounds__(256) void k_finalize(const double* __restrict__ ppart,
                                                  float* __restrict__ out) {
  int t = threadIdx.x;
  double s0 = 0.0, s1 = 0.0;
  for (int i = t; i < 1024; i += 256) {
    s0 += ppart[i];
    s1 += ppart[1024 + i];
  }
  __shared__ double a0[256], a1[256];
  a0[t] = s0;
  a1[t] = s1;
  __syncthreads();
  for (int off = 128; off > 0; off >>= 1) {
    if (t < off) {
      a0[t] += a0[t + off];
      a1[t] += a1[t + off];
    }
    __syncthreads();
  }
  if (t == 0) {
    out[N_OPS] = (float)a0[0];
    out[N_OPS + 1] = (float)a1[0];
  }
}

extern "C" void kernel_launch(void* const* d_in, const int* in_sizes, int n_in,
                              void* d_out, int out_size, void* d_ws, size_t ws_size,
                              hipStream_t stream) {
  const float* mem_logits = (const float*)d_in[0];
  const float* cw0 = (const float*)d_in[1];
  const float* cb0 = (const float*)d_in[2];
  const float* cw1 = (const float*)d_in[3];
  const float* cb1 = (const float*)d_in[4];
  const float* cw2 = (const float*)d_in[5];
  const float* cb2 = (const float*)d_in[6];
  const float* mw  = (const float*)d_in[7];
  const float* mbb = (const float*)d_in[8];
  const float* pw  = (const float*)d_in[9];
  const float* pb  = (const float*)d_in[10];
  float* out = (float*)d_out;
  char* ws = (char*)d_ws;

  u32* addr      = (u32*)(ws);
  u16* memfh     = (u16*)(ws + OFF_MEM);
  u32* kA        = (u32*)(ws + OFF_MEM);
  u32* kB        = (u32*)(ws + OFF_MEM + 9437184ull);
  u32* vB        = (u32*)(ws + OFF_MEM + 18874368ull);
  u32* counts    = (u32*)(ws + OFF_COUNTS);
  u32* pos       = (u32*)(ws + OFF_POS);
  float* partials= (float*)(ws + OFF_PART);
  float* flat    = (float*)(ws + OFF_FLAT);
  float* wt      = (float*)(ws + OFF_WT);
  double* ppart  = (double*)(ws + OFF_PPART);
  float4* ops    = (float4*)(ws + OFF_OPS);
  u32* k2A       = (u32*)(ws + OFF_MEM);
  u32* k2B       = (u32*)(ws + OFF_MEM + 1048576ull);
  u32* v2A       = (u32*)(ws + OFF_MEM + 2097152ull);
  u32* v2B       = (u32*)(ws + OFF_MEM + 3145728ull);

  // ---- sort 1 key-gen + weight transpose (fused) ----
  k_front<<<9217, 256, 0, stream>>>(mem_logits, kA, addr, mw, wt);
  const u32* ki[4] = {kA, kB, kA, kB};
  const u32* vi[4] = {addr, vB, addr, vB};
  u32* ko[4] = {kB, kA, kB, kA};
  u32* vo[4] = {vB, addr, vB, addr};
  for (int p = 0; p < 4; p++) {
    k_hist<<<576, 256, 0, stream>>>(ki[p], counts, p * 8, 576);
    k_scan_par<<<256, 256, 0, stream>>>(counts, pos, 576);
    k_scatter<<<576, 256, 0, stream>>>(ki[p], vi[p], ko[p], vo[p], pos, p * 8, 576,
                                       (p < 3) ? 1 : 0);
  }
  // final vals land in addr

  // ---- convs + bf16 scatter into memfh ----
  k_conv_scatter<<<4096, 256, 0, stream>>>(addr, cw0, cb0, memfh, 1024, 1024, 10, 0);
  k_conv_scatter<<<4096, 256, 0, stream>>>(addr, cw1, cb1, memfh, 1024, 1024, 10, OFF1);
  k_conv_scatter<<<1024, 256, 0, stream>>>(addr, cw2, cb2, memfh, 512, 512, 9, OFF2);

  // ---- mem conv (8->16) fused with 4x4 adaptive pool ----
  k_memconv<<<9216, 256, 0, stream>>>(memfh, wt, mbb, partials);
  k_pool_final<<<256, 256, 0, stream>>>(partials, flat);

  // ---- projection matvec -> op_logits ----
  k_matvec<<<2048, 256, 0, stream>>>(pw, pb, flat, out);

  // ---- sort 2 (memf dead now); last pass writes A-table in sorted order ----
  k_make_keys<<<1024, 256, 0, stream>>>(out, k2A, v2A, N_OPS);
  const u32* ki2[3] = {k2A, k2B, k2A};
  const u32* vi2[3] = {v2A, v2B, v2A};
  u32* ko2[3] = {k2B, k2A, k2B};
  u32* vo2[3] = {v2B, v2A, v2B};
  for (int p = 0; p < 3; p++) {
    k_hist<<<64, 256, 0, stream>>>(ki2[p], counts, p * 8, 64);
    k_scan_par<<<256, 256, 0, stream>>>(counts, pos, 64);
    k_scatter<<<64, 256, 0, stream>>>(ki2[p], vi2[p], ko2[p], vo2[p], pos, p * 8, 64, 1);
  }
  k_hist<<<64, 256, 0, stream>>>(k2B, counts, 24, 64);
  k_scan_par<<<256, 256, 0, stream>>>(counts, pos, 64);
  k_scatter_ops<<<64, 256, 0, stream>>>(k2B, v2B, pos, 24, 64, addr, ops);

  // ---- penalties (no atomics) ----
  k_penalty<<<1024, 256, 0, stream>>>(ops, ppart);
  k_finalize<<<1, 256, 0, stream>>>(ppart, out);
}

// Round 5
// 830.387 us; speedup vs baseline: 1.7733x; 1.2407x over previous
//
#include <hip/hip_runtime.h>
#include <cstdint>
#include <cstddef>

typedef unsigned int u32;
typedef unsigned short u16;
typedef unsigned long long u64;

#define NUM_EL 2359296
#define N_ROWS 294912
#define N_OPS  262144
#define OFF1   1048576
#define OFF2   2097152

// ---------------- workspace layout (bytes) ----------------
// addr:    [0, 9437184)            u32[NUM_EL]
// inv:     [9437184, 18874368)     u32[NUM_EL]   inv[addr[p]] = p
// feats8:  [18874368, 56623104)    bf16[NUM_EL*8] (37.75MB) -- sort1 scratch overlays:
//    kA=+0, kB=+9437184, v0=+18874368, v1=+28311552 (all dead before k_conv)
// counts:  [56623104, 56918016)    u32[256*288]
// pos:     [56918016, 57212928)    u32[256*288]
// part:    [57212928, 59572224)    float[64*9216]
// flat:    [59572224, 59573248)    float[256]
// wt:      [59573248, 59577856)    float[1152]
// ppart:   [59577856, 59594240)    double[2*1024]
// ops:     [59594240, 63788544)    float4[N_OPS]
// k2A/k2B/v2A/v2B: [63788544, +4MB)
#define OFF_INV    9437184ull
#define OFF_F8     18874368ull
#define OFF_COUNTS 56623104ull
#define OFF_POS    56918016ull
#define OFF_PART   57212928ull
#define OFF_FLAT   59572224ull
#define OFF_WT     59573248ull
#define OFF_PPART  59577856ull
#define OFF_OPS    59594240ull
#define OFF_S2     63788544ull

__device__ inline u32 pk_bf16(float a, float b) {  // RNE pack of 2 floats -> 2 bf16
  u32 ua = __float_as_uint(a), ub = __float_as_uint(b);
  ua = (ua + 0x7fffu + ((ua >> 16) & 1u)) >> 16;
  ub = (ub + 0x7fffu + ((ub >> 16) & 1u)) >> 16;
  return ua | (ub << 16);
}

// front: sort1 keys (blocks 0..9215) + weight transpose (block 9216). No vals (iota on the fly).
__global__ __launch_bounds__(256) void k_front(const float* __restrict__ x,
                                               u32* __restrict__ keys,
                                               const float* __restrict__ mw, float* __restrict__ wt) {
  if (blockIdx.x < 9216) {
    int i = blockIdx.x * 256 + threadIdx.x;
    u32 u = __float_as_uint(x[i]);
    u = (u & 0x80000000u) ? ~u : (u | 0x80000000u);
    keys[i] = u;
  } else {
    for (int i = threadIdx.x; i < 1152; i += 256) {
      int oc = i & 15;
      int rest = i >> 4;
      int ic = rest & 7;
      int p = rest >> 3;
      int dr = p / 3, dl = p % 3;
      wt[i] = mw[((oc * 8 + ic) * 3 + dr) * 3 + dl];
    }
  }
}

// 512 threads, 8192-elem tile, 16 keys/thread
__global__ __launch_bounds__(512) void k_hist(const u32* __restrict__ keys,
                                              u32* __restrict__ counts, int shift, int nB) {
  __shared__ u32 h[256];
  int t = threadIdx.x;
  if (t < 256) h[t] = 0;
  __syncthreads();
  int base = blockIdx.x * 8192;
#pragma unroll
  for (int k = 0; k < 16; k++) {
    u32 d = (keys[base + t + k * 512] >> shift) & 255u;
    atomicAdd(&h[d], 1u);
  }
  __syncthreads();
  if (t < 256) counts[t * nB + blockIdx.x] = h[t];  // digit-major
}

// 256 blocks (one per digit): base = sum counts[0, d*nB), then row scan in LDS.
__global__ __launch_bounds__(256) void k_scan_par(const u32* __restrict__ counts,
                                                  u32* __restrict__ pos, int nB) {
  int d = blockIdx.x, t = threadIdx.x;
  __shared__ u32 red[256];
  u32 s = 0;
  u32 lim = (u32)(d * nB);
  for (u32 i = t; i < lim; i += 256) s += counts[i];
  red[t] = s;
  __syncthreads();
  for (int off = 128; off > 0; off >>= 1) {
    if (t < off) red[t] += red[t + off];
    __syncthreads();
  }
  u32 base = red[0];
  __syncthreads();
  int chunk = (nB + 255) / 256;  // 2 for nB=288, 1 for nB=32
  int i0 = t * chunk;
  u32 loc[4];
  u32 lsum = 0;
#pragma unroll 4
  for (int k = 0; k < chunk; k++) {
    int i = i0 + k;
    u32 v = (i < nB) ? counts[d * nB + i] : 0u;
    loc[k] = lsum;
    lsum += v;
  }
  red[t] = lsum;
  __syncthreads();
  for (int off = 1; off < 256; off <<= 1) {
    u32 y = (t >= off) ? red[t - off] : 0u;
    __syncthreads();
    red[t] += y;
    __syncthreads();
  }
  u32 excl = red[t] - lsum;
#pragma unroll 4
  for (int k = 0; k < chunk; k++) {
    int i = i0 + k;
    if (i < nB) pos[d * nB + i] = base + excl + loc[k];
  }
}

// Stable scatter, 8192 tile, LDS reorder-by-digit -> coalesced global runs.
// gen_iota: vals = global index (pass 0, vin unused).
// mode: 0 = write keys+vals; 1 = write vals + inv[val]=gpos (final pass, keys dropped)
__global__ __launch_bounds__(512) void k_scatter(const u32* __restrict__ kin, const u32* __restrict__ vin,
                                                 u32* __restrict__ kout, u32* __restrict__ vout,
                                                 u32* __restrict__ invp,
                                                 const u32* __restrict__ gbase, int shift, int nB,
                                                 int gen_iota, int mode) {
  __shared__ u32 sk[8192], sv[8192];
  __shared__ u32 whist[8][256];
  __shared__ u32 sbase[256], lstart[256], gdelta[256], red[256];
  int t = threadIdx.x, b = blockIdx.x;
  int base = b * 8192;
  if (t < 256) {
#pragma unroll
    for (int w2 = 0; w2 < 8; w2++) whist[w2][t] = 0;
    sbase[t] = gbase[t * nB + b];
  }
  __syncthreads();
  int w = t >> 6, lane = t & 63;
  u64 lowmask = (1ull << lane) - 1ull;
  u32 kk[16], vv[16], dig[16], rnk[16];
#pragma unroll
  for (int j = 0; j < 16; j++) {
    int idx = base + w * 1024 + j * 64 + lane;
    kk[j] = kin[idx];
    vv[j] = gen_iota ? (u32)idx : vin[idx];
  }
#pragma unroll
  for (int j = 0; j < 16; j++) {
    u32 d = (kk[j] >> shift) & 255u;
    u64 m = ~0ull;
#pragma unroll
    for (int bit = 0; bit < 8; bit++) {
      u64 bal = __ballot((d >> bit) & 1u);
      m &= ((d >> bit) & 1u) ? bal : ~bal;
    }
    u32 rr = (u32)__popcll(m & lowmask);
    u32 cnt = (u32)__popcll(m);
    u32 prev = whist[w][d];        // wave-synchronous LDS read
    if (rr == 0) whist[w][d] = prev + cnt;
    dig[j] = d;
    rnk[j] = prev + rr;
  }
  __syncthreads();
  u32 tot = 0;
  if (t < 256) {
    u32 sacc = 0;
#pragma unroll
    for (int ww = 0; ww < 8; ww++) { u32 v = whist[ww][t]; whist[ww][t] = sacc; sacc += v; }
    tot = sacc;
    red[t] = tot;
  }
  __syncthreads();
  for (int off = 1; off < 256; off <<= 1) {
    u32 y = (t < 256 && t >= off) ? red[t - off] : 0u;
    __syncthreads();
    if (t < 256) red[t] += y;
    __syncthreads();
  }
  if (t < 256) {
    u32 lst = red[t] - tot;
    lstart[t] = lst;
    gdelta[t] = sbase[t] - lst;
  }
  __syncthreads();
#pragma unroll
  for (int j = 0; j < 16; j++) {
    u32 d = dig[j];
    u32 lpos = lstart[d] + whist[w][d] + rnk[j];
    sk[lpos] = kk[j];
    sv[lpos] = vv[j];
  }
  __syncthreads();
#pragma unroll
  for (int r = 0; r < 16; r++) {
    int idx = t + r * 512;
    u32 key = sk[idx];
    u32 d = (key >> shift) & 255u;
    u32 gpos = gdelta[d] + (u32)idx;
    u32 val = sv[idx];
    vout[gpos] = val;
    if (mode == 0) kout[gpos] = key;
    else invp[val] = gpos;
  }
}

// last sort2 pass: LDS reorder, then write A-table row float4(A0,A1,A2,0) at sorted pos
__global__ __launch_bounds__(512) void k_scatter_ops(const u32* __restrict__ kin, const u32* __restrict__ vin,
                                                     const u32* __restrict__ gbase, int shift, int nB,
                                                     const u32* __restrict__ addr, float4* __restrict__ ops) {
  __shared__ u32 sk[8192], sv[8192];
  __shared__ u32 whist[8][256];
  __shared__ u32 sbase[256], lstart[256], gdelta[256], red[256];
  int t = threadIdx.x, b = blockIdx.x;
  int base = b * 8192;
  if (t < 256) {
#pragma unroll
    for (int w2 = 0; w2 < 8; w2++) whist[w2][t] = 0;
    sbase[t] = gbase[t * nB + b];
  }
  __syncthreads();
  int w = t >> 6, lane = t & 63;
  u64 lowmask = (1ull << lane) - 1ull;
  u32 kk[16], vv[16], dig[16], rnk[16];
#pragma unroll
  for (int j = 0; j < 16; j++) {
    int idx = base + w * 1024 + j * 64 + lane;
    kk[j] = kin[idx];
    vv[j] = vin[idx];
  }
#pragma unroll
  for (int j = 0; j < 16; j++) {
    u32 d = (kk[j] >> shift) & 255u;
    u64 m = ~0ull;
#pragma unroll
    for (int bit = 0; bit < 8; bit++) {
      u64 bal = __ballot((d >> bit) & 1u);
      m &= ((d >> bit) & 1u) ? bal : ~bal;
    }
    u32 rr = (u32)__popcll(m & lowmask);
    u32 cnt = (u32)__popcll(m);
    u32 prev = whist[w][d];
    if (rr == 0) whist[w][d] = prev + cnt;
    dig[j] = d;
    rnk[j] = prev + rr;
  }
  __syncthreads();
  u32 tot = 0;
  if (t < 256) {
    u32 sacc = 0;
#pragma unroll
    for (int ww = 0; ww < 8; ww++) { u32 v = whist[ww][t]; whist[ww][t] = sacc; sacc += v; }
    tot = sacc;
    red[t] = tot;
  }
  __syncthreads();
  for (int off = 1; off < 256; off <<= 1) {
    u32 y = (t < 256 && t >= off) ? red[t - off] : 0u;
    __syncthreads();
    if (t < 256) red[t] += y;
    __syncthreads();
  }
  if (t < 256) {
    u32 lst = red[t] - tot;
    lstart[t] = lst;
    gdelta[t] = sbase[t] - lst;
  }
  __syncthreads();
#pragma unroll
  for (int j = 0; j < 16; j++) {
    u32 d = dig[j];
    u32 lpos = lstart[d] + whist[w][d] + rnk[j];
    sk[lpos] = kk[j];
    sv[lpos] = vv[j];
  }
  __syncthreads();
#pragma unroll
  for (int r = 0; r < 16; r++) {
    int idx = t + r * 512;
    u32 key = sk[idx];
    u32 d = (key >> shift) & 255u;
    u32 gpos = gdelta[d] + (u32)idx;
    u32 rv = sv[idx];
    int i = (int)(rv >> 9), jj = (int)(rv & 511);
    float A0 = (float)addr[(i << 10) + jj];
    float A1 = (float)addr[OFF1 + (i << 10) + jj];
    float A2 = (float)addr[OFF2 + (int)rv];
    ops[gpos] = make_float4(A0, A1, A2, 0.0f);
  }
}

// merged 3 convs: streaming 1->8ch 3x3 SAME on addr-as-float, relu, COALESCED bf16x8 write
__global__ __launch_bounds__(256) void k_conv(const u32* __restrict__ addr,
                                              const float* __restrict__ cw0, const float* __restrict__ cb0,
                                              const float* __restrict__ cw1, const float* __restrict__ cb1,
                                              const float* __restrict__ cw2, const float* __restrict__ cb2,
                                              u16* __restrict__ feats8) {
  int b = blockIdx.x;
  int H, W, lw, off;
  const float *cw, *cb;
  int pix;
  if (b < 4096)      { H = 1024; W = 1024; lw = 10; off = 0;    cw = cw0; cb = cb0; pix = b * 256; }
  else if (b < 8192) { H = 1024; W = 1024; lw = 10; off = OFF1; cw = cw1; cb = cb1; pix = (b - 4096) * 256; }
  else               { H = 512;  W = 512;  lw = 9;  off = OFF2; cw = cw2; cb = cb2; pix = (b - 8192) * 256; }
  pix += threadIdx.x;
  int i = pix >> lw, j = pix & (W - 1);
  float x[3][3];
#pragma unroll
  for (int dr = 0; dr < 3; dr++)
#pragma unroll
    for (int dc = 0; dc < 3; dc++) {
      int r = i + dr - 1, c = j + dc - 1;
      bool inb = ((unsigned)r < (unsigned)H) && ((unsigned)c < (unsigned)W);
      x[dr][dc] = inb ? (float)addr[off + r * W + c] : 0.0f;
    }
  float acc[8];
#pragma unroll
  for (int oc = 0; oc < 8; oc++) {
    float s = cb[oc];
#pragma unroll
    for (int dr = 0; dr < 3; dr++)
#pragma unroll
      for (int dc = 0; dc < 3; dc++)
        s = fmaf(x[dr][dc], cw[oc * 9 + dr * 3 + dc], s);
    acc[oc] = fmaxf(s, 0.0f);
  }
  uint4 pk;
  pk.x = pk_bf16(acc[0], acc[1]);
  pk.y = pk_bf16(acc[2], acc[3]);
  pk.z = pk_bf16(acc[4], acc[5]);
  pk.w = pk_bf16(acc[6], acc[7]);
  *(uint4*)(feats8 + (size_t)(off + pix) * 8) = pk;
}

// 8->16ch 3x3 conv + fused 4x4 pool. Tile staged by GATHER: column c's label = inv[c].
__global__ __launch_bounds__(256) void k_memconv(const u16* __restrict__ feats8,
                                                 const u32* __restrict__ inv,
                                                 const float* __restrict__ wt,
                                                 const float* __restrict__ mb,
                                                 float* __restrict__ partials) {
  __shared__ float tile[34 * 80];
  __shared__ float pool_s[256 * 17];
  int t = threadIdx.x;
  int r0 = blockIdx.x * 32;
  // stage 34 rows x 8 groups; group (rr,g) = mem column (r0-1+rr)*8+g
  for (int idx = t; idx < 34 * 8; idx += 256) {
    int rr = idx >> 3, g = idx & 7;
    int r = r0 - 1 + rr;
    float f[8];
    if ((unsigned)r < (unsigned)N_ROWS) {
      u32 L = inv[r * 8 + g];
      uint4 u = *(const uint4*)(feats8 + (size_t)L * 8);
      f[0] = __uint_as_float(u.x << 16); f[1] = __uint_as_float(u.x & 0xffff0000u);
      f[2] = __uint_as_float(u.y << 16); f[3] = __uint_as_float(u.y & 0xffff0000u);
      f[4] = __uint_as_float(u.z << 16); f[5] = __uint_as_float(u.z & 0xffff0000u);
      f[6] = __uint_as_float(u.w << 16); f[7] = __uint_as_float(u.w & 0xffff0000u);
    } else {
#pragma unroll
      for (int c = 0; c < 8; c++) f[c] = 0.0f;
    }
#pragma unroll
    for (int c = 0; c < 8; c++) tile[rr * 80 + (g + 1) * 8 + c] = f[c];
  }
  for (int idx = t; idx < 34 * 16; idx += 256) {
    int rr = idx >> 4, k = idx & 15;
    int col = (k < 8) ? k : (64 + k);
    tile[rr * 80 + col] = 0.0f;
  }
  __syncthreads();
  int lr = t >> 3, l = t & 7;
  float acc[16];
#pragma unroll
  for (int oc = 0; oc < 16; oc++) acc[oc] = mb[oc];
#pragma unroll
  for (int dr = 0; dr < 3; dr++) {
#pragma unroll
    for (int dl = 0; dl < 3; dl++) {
      const float* src = &tile[(lr + dr) * 80 + (l + dl) * 8];
      float4 a0 = *(const float4*)(src);
      float4 a1 = *(const float4*)(src + 4);
      float xv[8] = {a0.x, a0.y, a0.z, a0.w, a1.x, a1.y, a1.z, a1.w};
      const float* wp = &wt[(dr * 3 + dl) * 128];
#pragma unroll
      for (int ic = 0; ic < 8; ic++) {
#pragma unroll
        for (int oc = 0; oc < 16; oc++)
          acc[oc] = fmaf(xv[ic], wp[ic * 16 + oc], acc[oc]);
      }
    }
  }
#pragma unroll
  for (int oc = 0; oc < 16; oc++) pool_s[t * 17 + oc] = fmaxf(acc[oc], 0.0f);
  __syncthreads();
  if (t < 64) {
    int oc = t >> 2, lb = t & 3;
    float s = 0.0f;
    for (int lr2 = 0; lr2 < 32; lr2++) {
      int t2 = lr2 * 8 + lb * 2;
      s += pool_s[t2 * 17 + oc] + pool_s[(t2 + 1) * 17 + oc];
    }
    partials[(size_t)(oc * 4 + lb) * 9216 + blockIdx.x] = s;
  }
}

__global__ __launch_bounds__(256) void k_pool_final(const float* __restrict__ partials,
                                                    float* __restrict__ flat) {
  int f = blockIdx.x;
  int oc = f >> 4, rb = (f >> 2) & 3, lb = f & 3;
  const float* src = partials + (size_t)(oc * 4 + lb) * 9216 + rb * 2304;
  double s = 0.0;
  for (int i = threadIdx.x; i < 2304; i += 256) s += (double)src[i];
  __shared__ double sd[256];
  sd[threadIdx.x] = s;
  __syncthreads();
  for (int off = 128; off > 0; off >>= 1) {
    if (threadIdx.x < off) sd[threadIdx.x] += sd[threadIdx.x + off];
    __syncthreads();
  }
  if (threadIdx.x == 0) flat[f] = (float)(sd[0] * (1.0 / 147456.0));
}

// one wave per 32 rows of proj_w; also emits sort2 keys+vals
__global__ __launch_bounds__(256) void k_matvec(const float* __restrict__ pw,
                                                const float* __restrict__ pb,
                                                const float* __restrict__ flat,
                                                float* __restrict__ out,
                                                u32* __restrict__ k2, u32* __restrict__ v2) {
  int t = threadIdx.x;
  int lane = t & 63;
  int g = (blockIdx.x * 256 + t) >> 6;
  float4 f4 = ((const float4*)flat)[lane];
  int row0 = g * 32;
  for (int it = 0; it < 32; it += 2) {
    int row = row0 + it;
    float4 wa = ((const float4*)(pw + (size_t)row * 256))[lane];
    float4 wb = ((const float4*)(pw + (size_t)(row + 1) * 256))[lane];
    float sa = wa.x * f4.x + wa.y * f4.y + wa.z * f4.z + wa.w * f4.w;
    float sb = wb.x * f4.x + wb.y * f4.y + wb.z * f4.z + wb.w * f4.w;
#pragma unroll
    for (int off = 32; off > 0; off >>= 1) {
      sa += __shfl_xor(sa, off, 64);
      sb += __shfl_xor(sb, off, 64);
    }
    if (lane == 0) {
      float ra = sa + pb[row], rb2 = sb + pb[row + 1];
      out[row] = ra;
      out[row + 1] = rb2;
      u32 ua = __float_as_uint(ra), ub = __float_as_uint(rb2);
      ua = (ua & 0x80000000u) ? ~ua : (ua | 0x80000000u);
      ub = (ub & 0x80000000u) ? ~ub : (ub | 0x80000000u);
      k2[row] = ua; k2[row + 1] = ub;
      v2[row] = (u32)row; v2[row + 1] = (u32)(row + 1);
    }
  }
}

__device__ inline double staged_pair(float x) {
  float h = fabsf(x);
  double mult = (h <= 2.f) ? 1.0 : (h <= 4.f) ? 1.5 : (h <= 8.f) ? 2.0 : (h <= 16.f) ? 3.0 : 5.0;
  double hh = (double)h;
  if (x > 0.f) return hh * mult;
  if (x < 0.f) return hh * hh * mult;
  return 0.0;
}

__global__ __launch_bounds__(256) void k_penalty(const float4* __restrict__ ops,
                                                 double* __restrict__ ppart) {
  int k = blockIdx.x * 256 + threadIdx.x;
  float4 a = ops[k];
  double intra = staged_pair(a.y - a.x) + staged_pair(a.z - a.y);
  double inter = 0.0;
  if (k < N_OPS - 1) {
    float4 b = ops[k + 1];
    inter = staged_pair(b.x - a.z);
  }
  __shared__ double s0[256], s1[256];
  s0[threadIdx.x] = inter;
  s1[threadIdx.x] = intra;
  __syncthreads();
  for (int off = 128; off > 0; off >>= 1) {
    if (threadIdx.x < off) {
      s0[threadIdx.x] += s0[threadIdx.x + off];
      s1[threadIdx.x] += s1[threadIdx.x + off];
    }
    __syncthreads();
  }
  if (threadIdx.x == 0) {
    ppart[blockIdx.x] = s0[0];
    ppart[1024 + blockIdx.x] = s1[0];
  }
}

__global__ __launch_bounds__(256) void k_finalize(const double* __restrict__ ppart,
                                                  float* __restrict__ out) {
  int t = threadIdx.x;
  double s0 = 0.0, s1 = 0.0;
  for (int i = t; i < 1024; i += 256) {
    s0 += ppart[i];
    s1 += ppart[1024 + i];
  }
  __shared__ double a0[256], a1[256];
  a0[t] = s0;
  a1[t] = s1;
  __syncthreads();
  for (int off = 128; off > 0; off >>= 1) {
    if (t < off) {
      a0[t] += a0[t + off];
      a1[t] += a1[t + off];
    }
    __syncthreads();
  }
  if (t == 0) {
    out[N_OPS] = (float)a0[0];
    out[N_OPS + 1] = (float)a1[0];
  }
}

extern "C" void kernel_launch(void* const* d_in, const int* in_sizes, int n_in,
                              void* d_out, int out_size, void* d_ws, size_t ws_size,
                              hipStream_t stream) {
  const float* mem_logits = (const float*)d_in[0];
  const float* cw0 = (const float*)d_in[1];
  const float* cb0 = (const float*)d_in[2];
  const float* cw1 = (const float*)d_in[3];
  const float* cb1 = (const float*)d_in[4];
  const float* cw2 = (const float*)d_in[5];
  const float* cb2 = (const float*)d_in[6];
  const float* mw  = (const float*)d_in[7];
  const float* mbb = (const float*)d_in[8];
  const float* pw  = (const float*)d_in[9];
  const float* pb  = (const float*)d_in[10];
  float* out = (float*)d_out;
  char* ws = (char*)d_ws;

  u32* addr      = (u32*)(ws);
  u32* inv       = (u32*)(ws + OFF_INV);
  u16* feats8    = (u16*)(ws + OFF_F8);
  u32* kA        = (u32*)(ws + OFF_F8);
  u32* kB        = (u32*)(ws + OFF_F8 + 9437184ull);
  u32* v0        = (u32*)(ws + OFF_F8 + 18874368ull);
  u32* v1        = (u32*)(ws + OFF_F8 + 28311552ull);
  u32* counts    = (u32*)(ws + OFF_COUNTS);
  u32* pos       = (u32*)(ws + OFF_POS);
  float* partials= (float*)(ws + OFF_PART);
  float* flat    = (float*)(ws + OFF_FLAT);
  float* wt      = (float*)(ws + OFF_WT);
  double* ppart  = (double*)(ws + OFF_PPART);
  float4* ops    = (float4*)(ws + OFF_OPS);
  u32* k2A       = (u32*)(ws + OFF_S2);
  u32* k2B       = (u32*)(ws + OFF_S2 + 1048576ull);
  u32* v2A       = (u32*)(ws + OFF_S2 + 2097152ull);
  u32* v2B       = (u32*)(ws + OFF_S2 + 3145728ull);

  // ---- sort1: 3 passes over bits [8..32), stable; pass0 generates iota vals ----
  k_front<<<9217, 256, 0, stream>>>(mem_logits, kA, mw, wt);
  // pass 0: shift 8, (kA, iota) -> (kB, v0)
  k_hist<<<288, 512, 0, stream>>>(kA, counts, 8, 288);
  k_scan_par<<<256, 256, 0, stream>>>(counts, pos, 288);
  k_scatter<<<288, 512, 0, stream>>>(kA, nullptr, kB, v0, nullptr, pos, 8, 288, 1, 0);
  // pass 1: shift 16, (kB, v0) -> (kA, v1)
  k_hist<<<288, 512, 0, stream>>>(kB, counts, 16, 288);
  k_scan_par<<<256, 256, 0, stream>>>(counts, pos, 288);
  k_scatter<<<288, 512, 0, stream>>>(kB, v0, kA, v1, nullptr, pos, 16, 288, 0, 0);
  // pass 2: shift 24, (kA, v1) -> (addr) + inv
  k_hist<<<288, 512, 0, stream>>>(kA, counts, 24, 288);
  k_scan_par<<<256, 256, 0, stream>>>(counts, pos, 288);
  k_scatter<<<288, 512, 0, stream>>>(kA, v1, nullptr, addr, inv, pos, 24, 288, 0, 1);

  // ---- streaming convs (coalesced write), then gather-staged memconv + pool ----
  k_conv<<<9216, 256, 0, stream>>>(addr, cw0, cb0, cw1, cb1, cw2, cb2, feats8);
  k_memconv<<<9216, 256, 0, stream>>>(feats8, inv, wt, mbb, partials);
  k_pool_final<<<256, 256, 0, stream>>>(partials, flat);

  // ---- projection matvec -> op_logits + sort2 keys ----
  k_matvec<<<2048, 256, 0, stream>>>(pw, pb, flat, out, k2A, v2A);

  // ---- sort2: 3 passes over bits [8..32); final pass emits A-table ----
  k_hist<<<32, 512, 0, stream>>>(k2A, counts, 8, 32);
  k_scan_par<<<256, 256, 0, stream>>>(counts, pos, 32);
  k_scatter<<<32, 512, 0, stream>>>(k2A, v2A, k2B, v2B, nullptr, pos, 8, 32, 0, 0);
  k_hist<<<32, 512, 0, stream>>>(k2B, counts, 16, 32);
  k_scan_par<<<256, 256, 0, stream>>>(counts, pos, 32);
  k_scatter<<<32, 512, 0, stream>>>(k2B, v2B, k2A, v2A, nullptr, pos, 16, 32, 0, 0);
  k_hist<<<32, 512, 0, stream>>>(k2A, counts, 24, 32);
  k_scan_par<<<256, 256, 0, stream>>>(counts, pos, 32);
  k_scatter_ops<<<32, 512, 0, stream>>>(k2A, v2A, pos, 24, 32, addr, ops);

  // ---- penalties ----
  k_penalty<<<1024, 256, 0, stream>>>(ops, ppart);
  k_finalize<<<1, 256, 0, stream>>>(ppart, out);
}